// Round 1
// baseline (374.292 us; speedup 1.0000x reference)
//
#include <hip/hip_runtime.h>
#include <hip/hip_bf16.h>
#include <math.h>

typedef unsigned short u16;
typedef unsigned int u32;
typedef __attribute__((ext_vector_type(8))) short bf16x8;
typedef __attribute__((ext_vector_type(4))) float f32x4;

#define B_ 2
#define N_ 2048
#define D_ 2048
#define H_ 16
#define HD 128
#define GK 2048

__device__ __forceinline__ u16 f2bf(float f) {
  u32 u = __float_as_uint(f);
  u = (u + 0x7fffu + ((u >> 16) & 1u)) >> 16;  // RNE
  return (u16)u;
}

__device__ __forceinline__ void gload_lds16(const void* g, void* l) {
  __builtin_amdgcn_global_load_lds(
      (const __attribute__((address_space(1))) u32*)g,
      (__attribute__((address_space(3))) u32*)l, 16, 0, 0);
}

// ---------------- fp32 -> bf16 convert ----------------
__global__ __launch_bounds__(256) void cvt_kernel(const float* __restrict__ in,
                                                  u16* __restrict__ out, int n4) {
  int i = blockIdx.x * blockDim.x + threadIdx.x;
  int st = gridDim.x * blockDim.x;
  for (; i < n4; i += st) {
    float4 v = ((const float4*)in)[i];
    ushort4 o;
    o.x = f2bf(v.x); o.y = f2bf(v.y); o.z = f2bf(v.z); o.w = f2bf(v.w);
    ((ushort4*)out)[i] = o;
  }
}

// ---------------- RoPE cos/sin table: [pos][32] pairs ----------------
__global__ __launch_bounds__(256) void rope_tbl_kernel(float* __restrict__ tbl) {
  int i = blockIdx.x * blockDim.x + threadIdx.x;
  if (i >= N_ * 32) return;
  int pos = i >> 5, p = i & 31;
  double inv = pow(10000.0, -(double)p / 32.0);
  double a = (double)pos * inv;
  tbl[2 * i]     = (float)cos(a);
  tbl[2 * i + 1] = (float)sin(a);
}

// ---------------- QKV GEMM (128x128 tile, BK=32) + bias + RoPE + scatter ---
// C[m][n] = sum_k X[m][k] * W[n][k] + b[n]; m = b*2048+pos, n = sec*2048+h*128+d
__global__ __launch_bounds__(256) void qkv_gemm_kernel(
    const u16* __restrict__ X, const u16* __restrict__ W,
    const float* __restrict__ bias, const float* __restrict__ tbl,
    u16* __restrict__ Qo, u16* __restrict__ Ko, u16* __restrict__ Vo) {
  __shared__ u16 As[2][128 * 32];
  __shared__ u16 Bs[2][128 * 32];
  const int tid = threadIdx.x;
  const int lane = tid & 63;
  const int w = tid >> 6;
  const int wr = w >> 1, wc = w & 1;
  const int m0 = blockIdx.y * 128;
  const int n0 = blockIdx.x * 128;
  const int l15 = lane & 15, l4 = lane >> 4;

  f32x4 acc[4][4];
#pragma unroll
  for (int a = 0; a < 4; ++a)
#pragma unroll
    for (int b = 0; b < 4; ++b)
#pragma unroll
      for (int q = 0; q < 4; ++q) acc[a][b][q] = 0.f;

  // stage one K-step: 8 A-chunks + 8 B-chunks of 1KB; wave w -> chunks w*4..+3
  // LDS physical byte o; logical = o ^ (((o>>6)&3)<<4) (swizzle within 64B row)
  auto stage = [&](int buf, int k0) {
#pragma unroll
    for (int i = 0; i < 4; ++i) {
      int c = w * 4 + i;
      int cc = c & 7;
      int o = cc * 1024 + lane * 16;
      int lo = o ^ (((o >> 6) & 3) << 4);
      int row = lo >> 6;
      int kb2 = (lo & 63) >> 1;
      if (c < 8) {
        gload_lds16(X + (size_t)(m0 + row) * GK + k0 + kb2, As[buf] + cc * 512);
      } else {
        gload_lds16(W + (size_t)(n0 + row) * GK + k0 + kb2, Bs[buf] + cc * 512);
      }
    }
  };

  auto compute = [&](int buf) {
    bf16x8 a[4], b[4];
#pragma unroll
    for (int mf = 0; mf < 4; ++mf) {
      int row = wr * 64 + mf * 16 + l15;
      int off = (row * 64 + l4 * 16) ^ ((row & 3) << 4);
      a[mf] = *(const bf16x8*)((const char*)As[buf] + off);
    }
#pragma unroll
    for (int nf = 0; nf < 4; ++nf) {
      int row = wc * 64 + nf * 16 + l15;
      int off = (row * 64 + l4 * 16) ^ ((row & 3) << 4);
      b[nf] = *(const bf16x8*)((const char*)Bs[buf] + off);
    }
#pragma unroll
    for (int mf = 0; mf < 4; ++mf)
#pragma unroll
      for (int nf = 0; nf < 4; ++nf)
        acc[mf][nf] = __builtin_amdgcn_mfma_f32_16x16x32_bf16(a[mf], b[nf],
                                                              acc[mf][nf], 0, 0, 0);
  };

  stage(0, 0);
  __syncthreads();
  for (int kt = 0; kt < GK / 32; ++kt) {
    if (kt + 1 < GK / 32) stage((kt + 1) & 1, (kt + 1) * 32);
    compute(kt & 1);
    __syncthreads();
  }

  // epilogue: bias + RoPE (q,k sections, d<64) + scatter to [b][h][pos][d] bf16
#pragma unroll
  for (int nf = 0; nf < 4; ++nf) {
    int gn = n0 + wc * 64 + nf * 16 + l15;
    float bv = bias[gn];
    int sec = gn >> 11;
    int wi = gn & 2047;
    int h = wi >> 7;
    int d = wi & 127;
    u16* dstbase = (sec == 0) ? Qo : (sec == 1) ? Ko : Vo;
    bool doRope = (sec < 2) && (d < 64);
    int pidx = d >> 1;
    bool odd = (d & 1) != 0;
#pragma unroll
    for (int mf = 0; mf < 4; ++mf) {
#pragma unroll
      for (int j = 0; j < 4; ++j) {
        int gm = m0 + wr * 64 + mf * 16 + l4 * 4 + j;
        int bb = gm >> 11;
        int pos = gm & 2047;
        float v = acc[mf][nf][j] + bv;
        float pr = __shfl_xor(v, 1);  // partner column (d^1), same row
        float ov = v;
        if (doRope) {
          float2 cs = ((const float2*)tbl)[pos * 32 + pidx];
          ov = odd ? (v * cs.x + pr * cs.y) : (v * cs.x - pr * cs.y);
        }
        dstbase[(size_t)((bb * H_ + h) * N_ + pos) * HD + d] = f2bf(ov);
      }
    }
  }
}

// ---------------- causal flash attention ----------------
// block: 4 waves, 64 q-rows (16/wave); KV tiles of 64; Q/K/V bf16 [bh][n][128]
__global__ __launch_bounds__(256) void flash_kernel(
    const u16* __restrict__ Q, const u16* __restrict__ K, const u16* __restrict__ V,
    float* __restrict__ Out) {
  __shared__ u16 Kt[64 * 128];      // XOR-swizzled rows (256B), 16KB
  __shared__ u16 Vt[128 * 72];      // transposed [d][kv], stride 72, 18KB
  __shared__ u16 Pb[4][16 * 64];    // wave-private P, swizzled, 8KB

  const int tid = threadIdx.x, lane = tid & 63, w = tid >> 6;
  const int l15 = lane & 15, l4 = lane >> 4;
  const int bh = blockIdx.y;
  const int q0 = blockIdx.x * 64;
  const int bb = bh >> 4;
  const int h = bh & 15;
  const size_t base = (size_t)bh * (N_ * HD);

  bf16x8 qf[4];  // Q rows in registers: A-frag layout
  {
    const u16* qp = Q + base + (size_t)(q0 + w * 16 + l15) * HD + l4 * 8;
#pragma unroll
    for (int kf = 0; kf < 4; ++kf) qf[kf] = *(const bf16x8*)(qp + kf * 32);
  }

  float m_r[4], l_r[4];
  f32x4 accO[8];
#pragma unroll
  for (int j = 0; j < 4; ++j) { m_r[j] = -1e30f; l_r[j] = 0.f; }
#pragma unroll
  for (int df = 0; df < 8; ++df)
#pragma unroll
    for (int q = 0; q < 4; ++q) accO[df][q] = 0.f;

  const float scale = 0.08838834764831845f;  // 1/sqrt(128)
  const int nt = blockIdx.x + 1;

  for (int t = 0; t < nt; ++t) {
    const int t0 = t * 64;
    {  // stage K via global_load_lds, swizzled (rule #21: inverse-swz source)
      const u16* kb = K + base + (size_t)t0 * HD;
#pragma unroll
      for (int i = 0; i < 4; ++i) {
        int c = w * 4 + i;
        int o = c * 1024 + lane * 16;
        int lo = o ^ (((o >> 8) & 7) << 4);
        gload_lds16(kb + (lo >> 1), (char*)Kt + c * 1024);
      }
    }
    {  // stage V transposed: lane = kv row, wave covers 32 d
      const u16* vp = V + base + (size_t)(t0 + lane) * HD + w * 32;
#pragma unroll
      for (int i = 0; i < 4; ++i) {
        bf16x8 vv = *(const bf16x8*)(vp + i * 8);
#pragma unroll
        for (int jj = 0; jj < 8; ++jj)
          Vt[(w * 32 + i * 8 + jj) * 72 + lane] = (u16)vv[jj];
      }
    }
    __syncthreads();

    // S = Q K^T  (16 x 64 per wave)
    f32x4 s[4];
#pragma unroll
    for (int cf = 0; cf < 4; ++cf) {
#pragma unroll
      for (int q = 0; q < 4; ++q) s[cf][q] = 0.f;
      int row = cf * 16 + l15;
      int sw = (row & 7) << 4;
#pragma unroll
      for (int kf = 0; kf < 4; ++kf) {
        int off = (row * 256 + kf * 64 + l4 * 16) ^ sw;
        bf16x8 kfrag = *(const bf16x8*)((const char*)Kt + off);
        s[cf] = __builtin_amdgcn_mfma_f32_16x16x32_bf16(qf[kf], kfrag, s[cf], 0, 0, 0);
      }
    }

    // mask + online softmax
    const int rbase = q0 + w * 16 + l4 * 4;
    float pmax[4];
#pragma unroll
    for (int j = 0; j < 4; ++j) pmax[j] = -1e30f;
    float pv[4][4];
#pragma unroll
    for (int cf = 0; cf < 4; ++cf) {
      int colg = t0 + cf * 16 + l15;
#pragma unroll
      for (int j = 0; j < 4; ++j) {
        float sv = s[cf][j] * scale;
        if (colg > rbase + j) sv = -1e30f;
        pv[cf][j] = sv;
        pmax[j] = fmaxf(pmax[j], sv);
      }
    }
#pragma unroll
    for (int mm = 1; mm < 16; mm <<= 1)
#pragma unroll
      for (int j = 0; j < 4; ++j)
        pmax[j] = fmaxf(pmax[j], __shfl_xor(pmax[j], mm));

    float rs[4], psum[4];
#pragma unroll
    for (int j = 0; j < 4; ++j) {
      float mn = fmaxf(m_r[j], pmax[j]);
      rs[j] = __expf(m_r[j] - mn);
      m_r[j] = mn;
      psum[j] = 0.f;
    }
#pragma unroll
    for (int cf = 0; cf < 4; ++cf)
#pragma unroll
      for (int j = 0; j < 4; ++j) {
        float p = __expf(pv[cf][j] - m_r[j]);
        pv[cf][j] = p;
        psum[j] += p;
      }
#pragma unroll
    for (int mm = 1; mm < 16; mm <<= 1)
#pragma unroll
      for (int j = 0; j < 4; ++j) psum[j] += __shfl_xor(psum[j], mm);
#pragma unroll
    for (int j = 0; j < 4; ++j) l_r[j] = l_r[j] * rs[j] + psum[j];
#pragma unroll
    for (int df = 0; df < 8; ++df)
#pragma unroll
      for (int j = 0; j < 4; ++j) accO[df][j] *= rs[j];

    // P -> bf16 -> wave-private swizzled LDS -> A-frags; then PV
    {
      u16* pb = Pb[w];
#pragma unroll
      for (int cf = 0; cf < 4; ++cf)
#pragma unroll
        for (int j = 0; j < 4; ++j) {
          int rl = l4 * 4 + j;
          int off = (rl * 128 + (cf * 16 + l15) * 2) ^ ((rl & 7) << 4);
          *(u16*)((char*)pb + off) = f2bf(pv[cf][j]);
        }
      bf16x8 pf[2];
#pragma unroll
      for (int k2 = 0; k2 < 2; ++k2) {
        int off = (l15 * 128 + k2 * 64 + l4 * 16) ^ ((l15 & 7) << 4);
        pf[k2] = *(const bf16x8*)((const char*)pb + off);
      }
#pragma unroll
      for (int df = 0; df < 8; ++df) {
        int d = df * 16 + l15;
#pragma unroll
        for (int k2 = 0; k2 < 2; ++k2) {
          bf16x8 vf = *(const bf16x8*)(Vt + d * 72 + k2 * 32 + l4 * 8);
          accO[df] = __builtin_amdgcn_mfma_f32_16x16x32_bf16(pf[k2], vf, accO[df], 0, 0, 0);
        }
      }
    }
    __syncthreads();
  }

  // output: fp32, [b][pos][h*128+d]
  const int grow0 = q0 + w * 16 + l4 * 4;
#pragma unroll
  for (int df = 0; df < 8; ++df) {
    int d = h * HD + df * 16 + l15;
#pragma unroll
    for (int j = 0; j < 4; ++j) {
      Out[(size_t)(bb * N_ + grow0 + j) * D_ + d] = accO[df][j] / l_r[j];
    }
  }
}

extern "C" void kernel_launch(void* const* d_in, const int* in_sizes, int n_in,
                              void* d_out, int out_size, void* d_ws, size_t ws_size,
                              hipStream_t stream) {
  const float* x  = (const float*)d_in[0];
  const float* Wq = (const float*)d_in[1];
  const float* bq = (const float*)d_in[2];
  float* out = (float*)d_out;
  char* ws = (char*)d_ws;

  // workspace layout (bytes): Q 16MB | K 16MB | V 16MB | Xbf 16MB | Wbf 24MB | tbl 512KB
  u16* Qb  = (u16*)(ws);
  u16* Kb  = (u16*)(ws + 16777216);
  u16* Vb  = (u16*)(ws + 2 * 16777216);
  u16* Xb  = (u16*)(ws + 3 * 16777216);
  u16* Wb  = (u16*)(ws + 4 * 16777216);
  float* tbl = (float*)(ws + 4 * 16777216 + 25165824);

  cvt_kernel<<<2048, 256, 0, stream>>>(x, Xb, (B_ * N_ * D_) / 4);
  cvt_kernel<<<2048, 256, 0, stream>>>(Wq, Wb, (3 * D_ * D_) / 4);
  rope_tbl_kernel<<<(N_ * 32 + 255) / 256, 256, 0, stream>>>(tbl);
  qkv_gemm_kernel<<<dim3(48, 32), 256, 0, stream>>>(Xb, Wb, bq, tbl, Qb, Kb, Vb);
  flash_kernel<<<dim3(32, 32), 256, 0, stream>>>(Qb, Kb, Vb, out);
}

// Round 2
// 319.814 us; speedup vs baseline: 1.1703x; 1.1703x over previous
//
#include <hip/hip_runtime.h>
#include <hip/hip_bf16.h>
#include <math.h>

typedef unsigned short u16;
typedef unsigned int u32;
typedef __attribute__((ext_vector_type(8))) short bf16x8;
typedef __attribute__((ext_vector_type(4))) float f32x4;

#define B_ 2
#define N_ 2048
#define D_ 2048
#define H_ 16
#define HD 128
#define GK 2048

__device__ __forceinline__ u16 f2bf(float f) {
  u32 u = __float_as_uint(f);
  u = (u + 0x7fffu + ((u >> 16) & 1u)) >> 16;  // RNE
  return (u16)u;
}

__device__ __forceinline__ void gload_lds16(const void* g, void* l) {
  __builtin_amdgcn_global_load_lds(
      (const __attribute__((address_space(1))) u32*)g,
      (__attribute__((address_space(3))) u32*)l, 16, 0, 0);
}

// ---------------- fp32 -> bf16 convert ----------------
__global__ __launch_bounds__(256) void cvt_kernel(const float* __restrict__ in,
                                                  u16* __restrict__ out, int n4) {
  int i = blockIdx.x * blockDim.x + threadIdx.x;
  int st = gridDim.x * blockDim.x;
  for (; i < n4; i += st) {
    float4 v = ((const float4*)in)[i];
    ushort4 o;
    o.x = f2bf(v.x); o.y = f2bf(v.y); o.z = f2bf(v.z); o.w = f2bf(v.w);
    ((ushort4*)out)[i] = o;
  }
}

// ---------------- RoPE cos/sin table: [pos][32] pairs ----------------
__global__ __launch_bounds__(256) void rope_tbl_kernel(float* __restrict__ tbl) {
  int i = blockIdx.x * blockDim.x + threadIdx.x;
  if (i >= N_ * 32) return;
  int pos = i >> 5, p = i & 31;
  double inv = pow(10000.0, -(double)p / 32.0);
  double a = (double)pos * inv;
  tbl[2 * i]     = (float)cos(a);
  tbl[2 * i + 1] = (float)sin(a);
}

// ---------------- QKV GEMM (128x128 tile, BK=32) + bias + RoPE + scatter ---
__global__ __launch_bounds__(256) void qkv_gemm_kernel(
    const u16* __restrict__ X, const u16* __restrict__ W,
    const float* __restrict__ bias, const float* __restrict__ tbl,
    u16* __restrict__ Qo, u16* __restrict__ Ko, u16* __restrict__ Vo) {
  __shared__ u16 As[2][128 * 32];
  __shared__ u16 Bs[2][128 * 32];
  const int tid = threadIdx.x;
  const int lane = tid & 63;
  const int w = tid >> 6;
  const int wr = w >> 1, wc = w & 1;
  const int m0 = blockIdx.y * 128;
  const int n0 = blockIdx.x * 128;
  const int l15 = lane & 15, l4 = lane >> 4;

  f32x4 acc[4][4];
#pragma unroll
  for (int a = 0; a < 4; ++a)
#pragma unroll
    for (int b = 0; b < 4; ++b)
#pragma unroll
      for (int q = 0; q < 4; ++q) acc[a][b][q] = 0.f;

  auto stage = [&](int buf, int k0) {
#pragma unroll
    for (int i = 0; i < 4; ++i) {
      int c = w * 4 + i;
      int cc = c & 7;
      int o = cc * 1024 + lane * 16;
      int lo = o ^ (((o >> 6) & 3) << 4);
      int row = lo >> 6;
      int kb2 = (lo & 63) >> 1;
      if (c < 8) {
        gload_lds16(X + (size_t)(m0 + row) * GK + k0 + kb2, As[buf] + cc * 512);
      } else {
        gload_lds16(W + (size_t)(n0 + row) * GK + k0 + kb2, Bs[buf] + cc * 512);
      }
    }
  };

  auto compute = [&](int buf) {
    bf16x8 a[4], b[4];
#pragma unroll
    for (int mf = 0; mf < 4; ++mf) {
      int row = wr * 64 + mf * 16 + l15;
      int off = (row * 64 + l4 * 16) ^ ((row & 3) << 4);
      a[mf] = *(const bf16x8*)((const char*)As[buf] + off);
    }
#pragma unroll
    for (int nf = 0; nf < 4; ++nf) {
      int row = wc * 64 + nf * 16 + l15;
      int off = (row * 64 + l4 * 16) ^ ((row & 3) << 4);
      b[nf] = *(const bf16x8*)((const char*)Bs[buf] + off);
    }
#pragma unroll
    for (int mf = 0; mf < 4; ++mf)
#pragma unroll
      for (int nf = 0; nf < 4; ++nf)
        acc[mf][nf] = __builtin_amdgcn_mfma_f32_16x16x32_bf16(a[mf], b[nf],
                                                              acc[mf][nf], 0, 0, 0);
  };

  stage(0, 0);
  __syncthreads();
  for (int kt = 0; kt < GK / 32; ++kt) {
    if (kt + 1 < GK / 32) stage((kt + 1) & 1, (kt + 1) * 32);
    compute(kt & 1);
    __syncthreads();
  }

#pragma unroll
  for (int nf = 0; nf < 4; ++nf) {
    int gn = n0 + wc * 64 + nf * 16 + l15;
    float bv = bias[gn];
    int sec = gn >> 11;
    int wi = gn & 2047;
    int h = wi >> 7;
    int d = wi & 127;
    u16* dstbase = (sec == 0) ? Qo : (sec == 1) ? Ko : Vo;
    bool doRope = (sec < 2) && (d < 64);
    int pidx = d >> 1;
    bool odd = (d & 1) != 0;
#pragma unroll
    for (int mf = 0; mf < 4; ++mf) {
#pragma unroll
      for (int j = 0; j < 4; ++j) {
        int gm = m0 + wr * 64 + mf * 16 + l4 * 4 + j;
        int bb = gm >> 11;
        int pos = gm & 2047;
        float v = acc[mf][nf][j] + bv;
        float pr = __shfl_xor(v, 1);
        float ov = v;
        if (doRope) {
          float2 cs = ((const float2*)tbl)[pos * 32 + pidx];
          ov = odd ? (v * cs.x + pr * cs.y) : (v * cs.x - pr * cs.y);
        }
        dstbase[(size_t)((bb * H_ + h) * N_ + pos) * HD + d] = f2bf(ov);
      }
    }
  }
}

// ---------------- causal flash attention (swapped QK^T, in-register softmax)
// grid (16, 32): block x handles q-tiles x and 31-x (uniform 33 KV tiles).
// 4 waves x 16 q-rows. KVBLK=64. O^T = V^T * P^T, transposed out via LDS.
__global__ __launch_bounds__(256) void flash_kernel(
    const u16* __restrict__ Q, const u16* __restrict__ K, const u16* __restrict__ V,
    float* __restrict__ Out) {
  __shared__ char smem[34816];
  u16* Kt = (u16*)smem;               // 64x128 bf16, 256B rows XOR-swizzled
  u16* Vt = (u16*)(smem + 16384);     // transposed [d=128][kv=64+pad8], stride 72

  const int tid = threadIdx.x, lane = tid & 63, w = tid >> 6;
  const int l15 = lane & 15, l4 = lane >> 4;
  const int bh = blockIdx.y;
  const int bb = bh >> 4, h = bh & 15;
  const size_t base = (size_t)bh * (N_ * HD);
  float* Obuf = (float*)(smem + w * 8448);  // per-wave 16 x 132 f32

  const float scale = 0.08838834764831845f;  // 1/sqrt(128)
  const int x = blockIdx.x;
  const int src0 = l15 + 16 * (2 * (l4 & 1));
  const int src1 = src0 + 16;
  const int half = l4 >> 1;

  union U8 { u32 u[4]; bf16x8 v; };

  for (int ph = 0; ph < 2; ++ph) {
    const int qt = ph ? (31 - x) : x;
    const int q0 = qt * 64;

    bf16x8 qf[4];  // B-operand frags: col q = l15, k rows d = kf*32 + l4*8
    {
      const u16* qp = Q + base + (size_t)(q0 + w * 16 + l15) * HD + l4 * 8;
#pragma unroll
      for (int kf = 0; kf < 4; ++kf) qf[kf] = *(const bf16x8*)(qp + kf * 32);
    }

    float m_r = -1e30f, l_r = 0.f;
    f32x4 accO[8];
#pragma unroll
    for (int df = 0; df < 8; ++df)
#pragma unroll
      for (int q = 0; q < 4; ++q) accO[df][q] = 0.f;

    const int nt = qt + 1;
    for (int t = 0; t < nt; ++t) {
      const int t0 = t * 64;
      {  // stage K via global_load_lds, pre-swizzled source
        const u16* kb = K + base + (size_t)t0 * HD;
#pragma unroll
        for (int i = 0; i < 4; ++i) {
          int c = w * 4 + i;
          int o = c * 1024 + lane * 16;
          int lo = o ^ (((o >> 8) & 7) << 4);
          gload_lds16(kb + (lo >> 1), (char*)Kt + c * 1024);
        }
      }
      {  // stage V transposed: lane = kv row, wave covers 32 d-cols
        const u16* vp = V + base + (size_t)(t0 + lane) * HD + w * 32;
#pragma unroll
        for (int i = 0; i < 4; ++i) {
          bf16x8 vv = *(const bf16x8*)(vp + i * 8);
#pragma unroll
          for (int jj = 0; jj < 8; ++jj)
            Vt[(w * 32 + i * 8 + jj) * 72 + lane] = (u16)vv[jj];
        }
      }
      __syncthreads();

      // S^T = K Q^T: lane holds P[q=l15][kv = cf*16 + l4*4 + j]
      f32x4 s[4];
#pragma unroll
      for (int cf = 0; cf < 4; ++cf) {
#pragma unroll
        for (int q = 0; q < 4; ++q) s[cf][q] = 0.f;
        int row = cf * 16 + l15;
        int sw = (row & 7) << 4;
#pragma unroll
        for (int kf = 0; kf < 4; ++kf) {
          int off = (row * 256 + kf * 64 + l4 * 16) ^ sw;
          bf16x8 kfrag = *(const bf16x8*)((const char*)Kt + off);
          s[cf] = __builtin_amdgcn_mfma_f32_16x16x32_bf16(kfrag, qf[kf], s[cf], 0, 0, 0);
        }
      }

      // scale (+ mask on diagonal tile only)
      if (t == qt) {
        const int qg = q0 + w * 16 + l15;
#pragma unroll
        for (int cf = 0; cf < 4; ++cf)
#pragma unroll
          for (int j = 0; j < 4; ++j) {
            int kvg = t0 + cf * 16 + l4 * 4 + j;
            s[cf][j] = (kvg > qg) ? -1e30f : s[cf][j] * scale;
          }
      } else {
#pragma unroll
        for (int cf = 0; cf < 4; ++cf)
#pragma unroll
          for (int j = 0; j < 4; ++j) s[cf][j] *= scale;
      }

      // online softmax: in-lane over 16 + reduce across l4 groups (same q)
      float pmax = -1e30f;
#pragma unroll
      for (int cf = 0; cf < 4; ++cf)
#pragma unroll
        for (int j = 0; j < 4; ++j) pmax = fmaxf(pmax, s[cf][j]);
      pmax = fmaxf(pmax, __shfl_xor(pmax, 16));
      pmax = fmaxf(pmax, __shfl_xor(pmax, 32));

      float mn = fmaxf(m_r, pmax);
      float rs = __expf(m_r - mn);
      m_r = mn;

      u32 pk[4][2];
      float ps = 0.f;
#pragma unroll
      for (int cf = 0; cf < 4; ++cf) {
        float p0 = __expf(s[cf][0] - m_r);
        float p1 = __expf(s[cf][1] - m_r);
        float p2 = __expf(s[cf][2] - m_r);
        float p3 = __expf(s[cf][3] - m_r);
        ps += (p0 + p1) + (p2 + p3);
        pk[cf][0] = (u32)f2bf(p0) | ((u32)f2bf(p1) << 16);
        pk[cf][1] = (u32)f2bf(p2) | ((u32)f2bf(p3) << 16);
      }
      ps += __shfl_xor(ps, 16);
      ps += __shfl_xor(ps, 32);
      l_r = l_r * rs + ps;
#pragma unroll
      for (int df = 0; df < 8; ++df)
#pragma unroll
        for (int j = 0; j < 4; ++j) accO[df][j] *= rs;

      // PV: redistribute P^T into B-frags via shfl, A = V^T from Vt
#pragma unroll
      for (int c = 0; c < 2; ++c) {
        const int c2 = 2 * c;
        u32 a0 = (u32)__shfl((int)pk[c2][0], src0);
        u32 b0 = (u32)__shfl((int)pk[c2 + 1][0], src0);
        u32 a1 = (u32)__shfl((int)pk[c2][1], src0);
        u32 b1 = (u32)__shfl((int)pk[c2 + 1][1], src0);
        u32 a2 = (u32)__shfl((int)pk[c2][0], src1);
        u32 b2 = (u32)__shfl((int)pk[c2 + 1][0], src1);
        u32 a3 = (u32)__shfl((int)pk[c2][1], src1);
        u32 b3 = (u32)__shfl((int)pk[c2 + 1][1], src1);
        U8 pu;
        pu.u[0] = half ? b0 : a0;
        pu.u[1] = half ? b1 : a1;
        pu.u[2] = half ? b2 : a2;
        pu.u[3] = half ? b3 : a3;
#pragma unroll
        for (int df = 0; df < 8; ++df) {
          bf16x8 vf = *(const bf16x8*)(Vt + (df * 16 + l15) * 72 + c * 32 + l4 * 8);
          accO[df] = __builtin_amdgcn_mfma_f32_16x16x32_bf16(vf, pu.v, accO[df], 0, 0, 0);
        }
      }
      __syncthreads();
    }

    // epilogue: divide, transpose O^T -> O via per-wave LDS, coalesced store
    {
      float inv = 1.f / l_r;
#pragma unroll
      for (int df = 0; df < 8; ++df) {
        f32x4 v = accO[df];
#pragma unroll
        for (int j = 0; j < 4; ++j) v[j] *= inv;
        *(f32x4*)&Obuf[l15 * 132 + df * 16 + l4 * 4] = v;
      }
    }
    __syncthreads();
    {
      const int l31 = lane & 31;
#pragma unroll
      for (int p = 0; p < 8; ++p) {
        int row = p * 2 + (lane >> 5);
        f32x4 v = *(const f32x4*)&Obuf[row * 132 + l31 * 4];
        int qg = q0 + w * 16 + row;
        *(f32x4*)&Out[(size_t)(bb * N_ + qg) * D_ + h * HD + l31 * 4] = v;
      }
    }
    __syncthreads();
  }
}

extern "C" void kernel_launch(void* const* d_in, const int* in_sizes, int n_in,
                              void* d_out, int out_size, void* d_ws, size_t ws_size,
                              hipStream_t stream) {
  const float* x  = (const float*)d_in[0];
  const float* Wq = (const float*)d_in[1];
  const float* bq = (const float*)d_in[2];
  float* out = (float*)d_out;
  char* ws = (char*)d_ws;

  u16* Qb  = (u16*)(ws);
  u16* Kb  = (u16*)(ws + 16777216);
  u16* Vb  = (u16*)(ws + 2 * 16777216);
  u16* Xb  = (u16*)(ws + 3 * 16777216);
  u16* Wb  = (u16*)(ws + 4 * 16777216);
  float* tbl = (float*)(ws + 4 * 16777216 + 25165824);

  cvt_kernel<<<2048, 256, 0, stream>>>(x, Xb, (B_ * N_ * D_) / 4);
  cvt_kernel<<<2048, 256, 0, stream>>>(Wq, Wb, (3 * D_ * D_) / 4);
  rope_tbl_kernel<<<(N_ * 32 + 255) / 256, 256, 0, stream>>>(tbl);
  qkv_gemm_kernel<<<dim3(48, 32), 256, 0, stream>>>(Xb, Wb, bq, tbl, Qb, Kb, Vb);
  flash_kernel<<<dim3(16, 32), 256, 0, stream>>>(Qb, Kb, Vb, out);
}

// Round 3
// 265.476 us; speedup vs baseline: 1.4099x; 1.2047x over previous
//
#include <hip/hip_runtime.h>
#include <hip/hip_bf16.h>
#include <math.h>

typedef unsigned short u16;
typedef unsigned int u32;
typedef __attribute__((ext_vector_type(8))) short bf16x8;
typedef __attribute__((ext_vector_type(4))) float f32x4;

#define B_ 2
#define N_ 2048
#define D_ 2048
#define H_ 16
#define HD 128
#define GK 2048

__device__ __forceinline__ u16 f2bf(float f) {
  u32 u = __float_as_uint(f);
  u = (u + 0x7fffu + ((u >> 16) & 1u)) >> 16;  // RNE
  return (u16)u;
}

__device__ __forceinline__ u32 cvtpk(float lo, float hi) {
  u32 r;
  asm("v_cvt_pk_bf16_f32 %0, %1, %2" : "=v"(r) : "v"(lo), "v"(hi));
  return r;
}

__device__ __forceinline__ void gload_lds16(const void* g, void* l) {
  __builtin_amdgcn_global_load_lds(
      (const __attribute__((address_space(1))) u32*)g,
      (__attribute__((address_space(3))) u32*)l, 16, 0, 0);
}

// ---------------- fp32 -> bf16 convert ----------------
__global__ __launch_bounds__(256) void cvt_kernel(const float* __restrict__ in,
                                                  u16* __restrict__ out, int n4) {
  int i = blockIdx.x * blockDim.x + threadIdx.x;
  int st = gridDim.x * blockDim.x;
  for (; i < n4; i += st) {
    float4 v = ((const float4*)in)[i];
    ushort4 o;
    o.x = f2bf(v.x); o.y = f2bf(v.y); o.z = f2bf(v.z); o.w = f2bf(v.w);
    ((ushort4*)out)[i] = o;
  }
}

// ---------------- RoPE cos/sin table: [pos][32] pairs ----------------
__global__ __launch_bounds__(256) void rope_tbl_kernel(float* __restrict__ tbl) {
  int i = blockIdx.x * blockDim.x + threadIdx.x;
  if (i >= N_ * 32) return;
  int pos = i >> 5, p = i & 31;
  double inv = pow(10000.0, -(double)p / 32.0);
  double a = (double)pos * inv;
  tbl[2 * i]     = (float)cos(a);
  tbl[2 * i + 1] = (float)sin(a);
}

// ---------------- QKV GEMM (128x128 tile, BK=32) + bias + RoPE + scatter ---
// Q section additionally pre-scaled by 1/sqrt(hd) (folded softmax scale).
__global__ __launch_bounds__(256) void qkv_gemm_kernel(
    const u16* __restrict__ X, const u16* __restrict__ W,
    const float* __restrict__ bias, const float* __restrict__ tbl,
    u16* __restrict__ Qo, u16* __restrict__ Ko, u16* __restrict__ Vo) {
  __shared__ u16 As[2][128 * 32];
  __shared__ u16 Bs[2][128 * 32];
  const int tid = threadIdx.x;
  const int lane = tid & 63;
  const int w = tid >> 6;
  const int wr = w >> 1, wc = w & 1;
  const int m0 = blockIdx.y * 128;
  const int n0 = blockIdx.x * 128;
  const int l15 = lane & 15, l4 = lane >> 4;

  f32x4 acc[4][4];
#pragma unroll
  for (int a = 0; a < 4; ++a)
#pragma unroll
    for (int b = 0; b < 4; ++b)
#pragma unroll
      for (int q = 0; q < 4; ++q) acc[a][b][q] = 0.f;

  auto stage = [&](int buf, int k0) {
#pragma unroll
    for (int i = 0; i < 4; ++i) {
      int c = w * 4 + i;
      int cc = c & 7;
      int o = cc * 1024 + lane * 16;
      int lo = o ^ (((o >> 6) & 3) << 4);
      int row = lo >> 6;
      int kb2 = (lo & 63) >> 1;
      if (c < 8) {
        gload_lds16(X + (size_t)(m0 + row) * GK + k0 + kb2, As[buf] + cc * 512);
      } else {
        gload_lds16(W + (size_t)(n0 + row) * GK + k0 + kb2, Bs[buf] + cc * 512);
      }
    }
  };

  auto compute = [&](int buf) {
    bf16x8 a[4], b[4];
#pragma unroll
    for (int mf = 0; mf < 4; ++mf) {
      int row = wr * 64 + mf * 16 + l15;
      int off = (row * 64 + l4 * 16) ^ ((row & 3) << 4);
      a[mf] = *(const bf16x8*)((const char*)As[buf] + off);
    }
#pragma unroll
    for (int nf = 0; nf < 4; ++nf) {
      int row = wc * 64 + nf * 16 + l15;
      int off = (row * 64 + l4 * 16) ^ ((row & 3) << 4);
      b[nf] = *(const bf16x8*)((const char*)Bs[buf] + off);
    }
#pragma unroll
    for (int mf = 0; mf < 4; ++mf)
#pragma unroll
      for (int nf = 0; nf < 4; ++nf)
        acc[mf][nf] = __builtin_amdgcn_mfma_f32_16x16x32_bf16(a[mf], b[nf],
                                                              acc[mf][nf], 0, 0, 0);
  };

  stage(0, 0);
  __syncthreads();
  for (int kt = 0; kt < GK / 32; ++kt) {
    if (kt + 1 < GK / 32) stage((kt + 1) & 1, (kt + 1) * 32);
    compute(kt & 1);
    __syncthreads();
  }

  const float QSCALE = 0.08838834764831845f;  // 1/sqrt(128)
#pragma unroll
  for (int nf = 0; nf < 4; ++nf) {
    int gn = n0 + wc * 64 + nf * 16 + l15;
    float bv = bias[gn];
    int sec = gn >> 11;
    int wi = gn & 2047;
    int h = wi >> 7;
    int d = wi & 127;
    u16* dstbase = (sec == 0) ? Qo : (sec == 1) ? Ko : Vo;
    float mulf = (sec == 0) ? QSCALE : 1.f;
    bool doRope = (sec < 2) && (d < 64);
    int pidx = d >> 1;
    bool odd = (d & 1) != 0;
#pragma unroll
    for (int mf = 0; mf < 4; ++mf) {
#pragma unroll
      for (int j = 0; j < 4; ++j) {
        int gm = m0 + wr * 64 + mf * 16 + l4 * 4 + j;
        int bb = gm >> 11;
        int pos = gm & 2047;
        float v = acc[mf][nf][j] + bv;
        float pr = __shfl_xor(v, 1);
        float ov = v;
        if (doRope) {
          float2 cs = ((const float2*)tbl)[pos * 32 + pidx];
          ov = odd ? (v * cs.x + pr * cs.y) : (v * cs.x - pr * cs.y);
        }
        dstbase[(size_t)((bb * H_ + h) * N_ + pos) * HD + d] = f2bf(ov * mulf);
      }
    }
  }
}

// ---------------- causal flash attention ----------------
// 512 blocks (1-D), 4 waves x 32 q-rows = 128 q-rows/block. KVBLK=64,
// double-buffered K/V, one barrier/tile, T14 staged V, defer-max softmax.
// LPT dispatch (longest tiles first) + XCD-chunked bh mapping for L2.
__global__ __launch_bounds__(256, 2) void flash_kernel(
    const u16* __restrict__ Q, const u16* __restrict__ K, const u16* __restrict__ V,
    float* __restrict__ Out) {
  __shared__ char smem[69632];  // K dbuf 2x16KB | V dbuf 2x18KB

  const int tid = threadIdx.x, lane = tid & 63, w = tid >> 6;
  const int l15 = lane & 15, l4 = lane >> 4;

  const int bid = blockIdx.x;
  const int xcd = bid & 7, slot = bid >> 3;
  const int bh = xcd * 4 + (slot >> 4);   // 4 bh per XCD -> K/V fits 4MB L2
  const int x = 15 - (slot & 15);         // LPT: longest q-tiles dispatch first
  const int bb = bh >> 4, h = bh & 15;
  const size_t base = (size_t)bh * (N_ * HD);
  const int q0 = x * 128;
  const int nt = 2 * x + 2;

  // Q B-frags for two 16-row groups (col q = l15, k rows d = kf*32 + l4*8)
  bf16x8 qf[2][4];
#pragma unroll
  for (int g = 0; g < 2; ++g) {
    const u16* qp = Q + base + (size_t)(q0 + w * 32 + g * 16 + l15) * HD + l4 * 8;
#pragma unroll
    for (int kf = 0; kf < 4; ++kf) qf[g][kf] = *(const bf16x8*)(qp + kf * 32);
  }

  float m_r[2] = {-1e30f, -1e30f}, l_r[2] = {0.f, 0.f};
  f32x4 accO[2][8];
#pragma unroll
  for (int g = 0; g < 2; ++g)
#pragma unroll
    for (int df = 0; df < 8; ++df)
#pragma unroll
      for (int q = 0; q < 4; ++q) accO[g][df][q] = 0.f;

  auto stageK = [&](int buf, int t0) {
    const u16* kb = K + base + (size_t)t0 * HD;
    char* kt = smem + buf * 16384;
#pragma unroll
    for (int i = 0; i < 4; ++i) {
      int c = w * 4 + i;
      int o = c * 1024 + lane * 16;
      int lo = o ^ (((o >> 8) & 7) << 4);
      gload_lds16(kb + (lo >> 1), kt + c * 1024);
    }
  };
  auto loadV = [&](int t0, bf16x8* vr) {
    const u16* vp = V + base + (size_t)(t0 + lane) * HD + w * 32;
#pragma unroll
    for (int i = 0; i < 4; ++i) vr[i] = *(const bf16x8*)(vp + i * 8);
  };
  auto writeV = [&](int buf, const bf16x8* vr) {
    u16* vt = (u16*)(smem + 32768 + buf * 18432);
#pragma unroll
    for (int i = 0; i < 4; ++i)
#pragma unroll
      for (int jj = 0; jj < 8; ++jj)
        vt[(w * 32 + i * 8 + jj) * 72 + lane] = (u16)vr[i][jj];
  };

  const int src0 = l15 + 32 * (l4 & 1);
  const int src1 = src0 + 16;
  const int half = l4 >> 1;
  union U8 { u32 u[4]; bf16x8 v; };

  bf16x8 vreg[4];
  stageK(0, 0);
  loadV(0, vreg);
  writeV(0, vreg);
  __syncthreads();

  for (int t = 0; t < nt; ++t) {
    const int cur = t & 1;
    const int t0 = t * 64;
    const bool pre = (t + 1 < nt);
    if (pre) { stageK(cur ^ 1, t0 + 64); loadV(t0 + 64, vreg); }

    const char* kt = smem + cur * 16384;
    const u16* vt = (const u16*)(smem + 32768 + cur * 18432);

    // S^T = K Q^T: lane holds S[kv = cf*16 + l4*4 + j][q = l15] per group
    f32x4 s[2][4];
#pragma unroll
    for (int cf = 0; cf < 4; ++cf) {
#pragma unroll
      for (int q = 0; q < 4; ++q) { s[0][cf][q] = 0.f; s[1][cf][q] = 0.f; }
      int row = cf * 16 + l15;
      int sw = (row & 7) << 4;
#pragma unroll
      for (int kf = 0; kf < 4; ++kf) {
        int off = (row * 256 + kf * 64 + l4 * 16) ^ sw;
        bf16x8 kfrag = *(const bf16x8*)(kt + off);
        s[0][cf] = __builtin_amdgcn_mfma_f32_16x16x32_bf16(kfrag, qf[0][kf], s[0][cf], 0, 0, 0);
        s[1][cf] = __builtin_amdgcn_mfma_f32_16x16x32_bf16(kfrag, qf[1][kf], s[1][cf], 0, 0, 0);
      }
    }

    u32 pk[2][4][2];
#pragma unroll
    for (int g = 0; g < 2; ++g) {
      const int qbase = q0 + w * 32 + g * 16;
      if (t0 + 63 > qbase) {  // diagonal: causal mask
        const int qg = qbase + l15;
#pragma unroll
        for (int cf = 0; cf < 4; ++cf)
#pragma unroll
          for (int j = 0; j < 4; ++j) {
            int kvg = t0 + cf * 16 + l4 * 4 + j;
            if (kvg > qg) s[g][cf][j] = -1e30f;
          }
      }
      // per-q max: in-lane 16 + cross-group reduce
      float pmax = s[g][0][0];
#pragma unroll
      for (int cf = 0; cf < 4; ++cf)
#pragma unroll
        for (int j = 0; j < 4; ++j) pmax = fmaxf(pmax, s[g][cf][j]);
      pmax = fmaxf(pmax, __shfl_xor(pmax, 16));
      pmax = fmaxf(pmax, __shfl_xor(pmax, 32));

      if (!__all(pmax <= m_r[g] + 8.f)) {  // T13 defer-max
        float mn = fmaxf(m_r[g], pmax);
        float rs = __expf(m_r[g] - mn);
        m_r[g] = mn;
        l_r[g] *= rs;
#pragma unroll
        for (int df = 0; df < 8; ++df)
#pragma unroll
          for (int j = 0; j < 4; ++j) accO[g][df][j] *= rs;
      }

      float ps = 0.f;
#pragma unroll
      for (int cf = 0; cf < 4; ++cf) {
        float p0 = __expf(s[g][cf][0] - m_r[g]);
        float p1 = __expf(s[g][cf][1] - m_r[g]);
        float p2 = __expf(s[g][cf][2] - m_r[g]);
        float p3 = __expf(s[g][cf][3] - m_r[g]);
        ps += (p0 + p1) + (p2 + p3);
        pk[g][cf][0] = cvtpk(p0, p1);
        pk[g][cf][1] = cvtpk(p2, p3);
      }
      ps += __shfl_xor(ps, 16);
      ps += __shfl_xor(ps, 32);
      l_r[g] += ps;
    }

    // PV: O^T += V^T P^T ; V^T frags shared across both q-groups
#pragma unroll
    for (int c = 0; c < 2; ++c) {
      const int c2 = 2 * c;
      U8 pu[2];
#pragma unroll
      for (int g = 0; g < 2; ++g) {
        u32 a0 = (u32)__shfl((int)pk[g][c2][0], src0);
        u32 b0 = (u32)__shfl((int)pk[g][c2 + 1][0], src0);
        u32 a1 = (u32)__shfl((int)pk[g][c2][1], src0);
        u32 b1 = (u32)__shfl((int)pk[g][c2 + 1][1], src0);
        u32 a2 = (u32)__shfl((int)pk[g][c2][0], src1);
        u32 b2 = (u32)__shfl((int)pk[g][c2 + 1][0], src1);
        u32 a3 = (u32)__shfl((int)pk[g][c2][1], src1);
        u32 b3 = (u32)__shfl((int)pk[g][c2 + 1][1], src1);
        pu[g].u[0] = half ? b0 : a0;
        pu[g].u[1] = half ? b1 : a1;
        pu[g].u[2] = half ? b2 : a2;
        pu[g].u[3] = half ? b3 : a3;
      }
#pragma unroll
      for (int df = 0; df < 8; ++df) {
        bf16x8 vf = *(const bf16x8*)(vt + (df * 16 + l15) * 72 + c * 32 + l4 * 8);
        accO[0][df] = __builtin_amdgcn_mfma_f32_16x16x32_bf16(vf, pu[0].v, accO[0][df], 0, 0, 0);
        accO[1][df] = __builtin_amdgcn_mfma_f32_16x16x32_bf16(vf, pu[1].v, accO[1][df], 0, 0, 0);
      }
    }

    if (pre) writeV(cur ^ 1, vreg);  // T14: write-late after PV
    __syncthreads();
  }

  // epilogue: divide, transpose O^T -> O via per-wave LDS, coalesced store
  float* Obuf = (float*)(smem + w * 8448);  // 16 x 132 f32, wave-private
  const int l31 = lane & 31;
#pragma unroll
  for (int g = 0; g < 2; ++g) {
    float inv = 1.f / l_r[g];
#pragma unroll
    for (int df = 0; df < 8; ++df) {
      f32x4 v = accO[g][df];
#pragma unroll
      for (int j = 0; j < 4; ++j) v[j] *= inv;
      *(f32x4*)&Obuf[l15 * 132 + df * 16 + l4 * 4] = v;
    }
#pragma unroll
    for (int p = 0; p < 8; ++p) {
      int row = p * 2 + (lane >> 5);
      f32x4 v = *(const f32x4*)&Obuf[row * 132 + l31 * 4];
      int qg = q0 + w * 32 + g * 16 + row;
      *(f32x4*)&Out[(size_t)(bb * N_ + qg) * D_ + h * HD + l31 * 4] = v;
    }
  }
}

extern "C" void kernel_launch(void* const* d_in, const int* in_sizes, int n_in,
                              void* d_out, int out_size, void* d_ws, size_t ws_size,
                              hipStream_t stream) {
  const float* x  = (const float*)d_in[0];
  const float* Wq = (const float*)d_in[1];
  const float* bq = (const float*)d_in[2];
  float* out = (float*)d_out;
  char* ws = (char*)d_ws;

  u16* Qb  = (u16*)(ws);
  u16* Kb  = (u16*)(ws + 16777216);
  u16* Vb  = (u16*)(ws + 2 * 16777216);
  u16* Xb  = (u16*)(ws + 3 * 16777216);
  u16* Wb  = (u16*)(ws + 4 * 16777216);
  float* tbl = (float*)(ws + 4 * 16777216 + 25165824);

  cvt_kernel<<<2048, 256, 0, stream>>>(x, Xb, (B_ * N_ * D_) / 4);
  cvt_kernel<<<2048, 256, 0, stream>>>(Wq, Wb, (3 * D_ * D_) / 4);
  rope_tbl_kernel<<<(N_ * 32 + 255) / 256, 256, 0, stream>>>(tbl);
  qkv_gemm_kernel<<<dim3(48, 32), 256, 0, stream>>>(Xb, Wb, bq, tbl, Qb, Kb, Vb);
  flash_kernel<<<512, 256, 0, stream>>>(Qb, Kb, Vb, out);
}

// Round 4
// 264.737 us; speedup vs baseline: 1.4138x; 1.0028x over previous
//
#include <hip/hip_runtime.h>
#include <hip/hip_bf16.h>
#include <math.h>

typedef unsigned short u16;
typedef unsigned int u32;
typedef __attribute__((ext_vector_type(8))) short bf16x8;
typedef __attribute__((ext_vector_type(4))) float f32x4;

#define B_ 2
#define N_ 2048
#define D_ 2048
#define H_ 16
#define HD 128
#define GK 2048

__device__ __forceinline__ u16 f2bf(float f) {
  u32 u = __float_as_uint(f);
  u = (u + 0x7fffu + ((u >> 16) & 1u)) >> 16;  // RNE
  return (u16)u;
}

__device__ __forceinline__ u32 cvtpk(float lo, float hi) {
  u32 r;
  asm("v_cvt_pk_bf16_f32 %0, %1, %2" : "=v"(r) : "v"(lo), "v"(hi));
  return r;
}

__device__ __forceinline__ void gload_lds16(const void* g, void* l) {
  __builtin_amdgcn_global_load_lds(
      (const __attribute__((address_space(1))) u32*)g,
      (__attribute__((address_space(3))) u32*)l, 16, 0, 0);
}

// ---------------- fp32 -> bf16 convert ----------------
__global__ __launch_bounds__(256) void cvt_kernel(const float* __restrict__ in,
                                                  u16* __restrict__ out, int n4) {
  int i = blockIdx.x * blockDim.x + threadIdx.x;
  int st = gridDim.x * blockDim.x;
  for (; i < n4; i += st) {
    float4 v = ((const float4*)in)[i];
    ushort4 o;
    o.x = f2bf(v.x); o.y = f2bf(v.y); o.z = f2bf(v.z); o.w = f2bf(v.w);
    ((ushort4*)out)[i] = o;
  }
}

// ---------------- RoPE cos/sin table: [pos][32] pairs ----------------
__global__ __launch_bounds__(256) void rope_tbl_kernel(float* __restrict__ tbl) {
  int i = blockIdx.x * blockDim.x + threadIdx.x;
  if (i >= N_ * 32) return;
  int pos = i >> 5, p = i & 31;
  double inv = pow(10000.0, -(double)p / 32.0);
  double a = (double)pos * inv;
  tbl[2 * i]     = (float)cos(a);
  tbl[2 * i + 1] = (float)sin(a);
}

// ---------------- QKV GEMM (128x128 tile, BK=32) + bias + RoPE + scatter ---
// LDS rows are 64B; banks repeat every 2 rows -> swizzle slot = (row>>1)&3
// (row&3 left even rows on 2 slots = 4-way conflict; this is the fix).
__global__ __launch_bounds__(256) void qkv_gemm_kernel(
    const u16* __restrict__ X, const u16* __restrict__ W,
    const float* __restrict__ bias, const float* __restrict__ tbl,
    u16* __restrict__ Qo, u16* __restrict__ Ko, u16* __restrict__ Vo) {
  __shared__ u16 As[2][128 * 32];
  __shared__ u16 Bs[2][128 * 32];
  const int tid = threadIdx.x;
  const int lane = tid & 63;
  const int w = tid >> 6;
  const int wr = w >> 1, wc = w & 1;
  const int m0 = blockIdx.y * 128;
  const int n0 = blockIdx.x * 128;
  const int l15 = lane & 15, l4 = lane >> 4;

  f32x4 acc[4][4];
#pragma unroll
  for (int a = 0; a < 4; ++a)
#pragma unroll
    for (int b = 0; b < 4; ++b)
#pragma unroll
      for (int q = 0; q < 4; ++q) acc[a][b][q] = 0.f;

  auto stage = [&](int buf, int k0) {
#pragma unroll
    for (int i = 0; i < 4; ++i) {
      int c = w * 4 + i;
      int cc = c & 7;
      int o = cc * 1024 + lane * 16;
      int lo = o ^ (((o >> 7) & 3) << 4);   // inverse of read-side swizzle
      int row = lo >> 6;
      int kb2 = (lo & 63) >> 1;
      if (c < 8) {
        gload_lds16(X + (size_t)(m0 + row) * GK + k0 + kb2, As[buf] + cc * 512);
      } else {
        gload_lds16(W + (size_t)(n0 + row) * GK + k0 + kb2, Bs[buf] + cc * 512);
      }
    }
  };

  auto compute = [&](int buf) {
    bf16x8 a[4], b[4];
#pragma unroll
    for (int mf = 0; mf < 4; ++mf) {
      int row = wr * 64 + mf * 16 + l15;
      int off = (row * 64 + l4 * 16) ^ (((row >> 1) & 3) << 4);
      a[mf] = *(const bf16x8*)((const char*)As[buf] + off);
    }
#pragma unroll
    for (int nf = 0; nf < 4; ++nf) {
      int row = wc * 64 + nf * 16 + l15;
      int off = (row * 64 + l4 * 16) ^ (((row >> 1) & 3) << 4);
      b[nf] = *(const bf16x8*)((const char*)Bs[buf] + off);
    }
#pragma unroll
    for (int mf = 0; mf < 4; ++mf)
#pragma unroll
      for (int nf = 0; nf < 4; ++nf)
        acc[mf][nf] = __builtin_amdgcn_mfma_f32_16x16x32_bf16(a[mf], b[nf],
                                                              acc[mf][nf], 0, 0, 0);
  };

  stage(0, 0);
  __syncthreads();
  for (int kt = 0; kt < GK / 32; ++kt) {
    if (kt + 1 < GK / 32) stage((kt + 1) & 1, (kt + 1) * 32);
    compute(kt & 1);
    __syncthreads();
  }

  const float QSCALE = 0.08838834764831845f;  // 1/sqrt(128)
#pragma unroll
  for (int nf = 0; nf < 4; ++nf) {
    int gn = n0 + wc * 64 + nf * 16 + l15;
    float bv = bias[gn];
    int sec = gn >> 11;
    int wi = gn & 2047;
    int h = wi >> 7;
    int d = wi & 127;
    u16* dstbase = (sec == 0) ? Qo : (sec == 1) ? Ko : Vo;
    float mulf = (sec == 0) ? QSCALE : 1.f;
    bool doRope = (sec < 2) && (d < 64);
    int pidx = d >> 1;
    bool odd = (d & 1) != 0;
#pragma unroll
    for (int mf = 0; mf < 4; ++mf) {
#pragma unroll
      for (int j = 0; j < 4; ++j) {
        int gm = m0 + wr * 64 + mf * 16 + l4 * 4 + j;
        int bb = gm >> 11;
        int pos = gm & 2047;
        float v = acc[mf][nf][j] + bv;
        float pr = __shfl_xor(v, 1);
        float ov = v;
        if (doRope) {
          float2 cs = ((const float2*)tbl)[pos * 32 + pidx];
          ov = odd ? (v * cs.x + pr * cs.y) : (v * cs.x - pr * cs.y);
        }
        dstbase[(size_t)((bb * H_ + h) * N_ + pos) * HD + d] = f2bf(ov * mulf);
      }
    }
  }
}

// ---------------- causal flash attention ----------------
// 512 blocks (1-D), 4 waves x 32 q-rows = 128 q-rows/block. KVBLK=64,
// double-buffered K/V, one barrier/tile, T14 staged V, defer-max softmax.
// LPT dispatch (longest tiles first) + XCD-chunked bh mapping for L2.
__global__ __launch_bounds__(256, 2) void flash_kernel(
    const u16* __restrict__ Q, const u16* __restrict__ K, const u16* __restrict__ V,
    float* __restrict__ Out) {
  __shared__ char smem[69632];  // K dbuf 2x16KB | V dbuf 2x18KB

  const int tid = threadIdx.x, lane = tid & 63, w = tid >> 6;
  const int l15 = lane & 15, l4 = lane >> 4;

  const int bid = blockIdx.x;
  const int xcd = bid & 7, slot = bid >> 3;
  const int bh = xcd * 4 + (slot >> 4);   // 4 bh per XCD -> K/V fits 4MB L2
  const int x = 15 - (slot & 15);         // LPT: longest q-tiles dispatch first
  const int bb = bh >> 4, h = bh & 15;
  const size_t base = (size_t)bh * (N_ * HD);
  const int q0 = x * 128;
  const int nt = 2 * x + 2;

  // Q B-frags for two 16-row groups (col q = l15, k rows d = kf*32 + l4*8)
  bf16x8 qf[2][4];
#pragma unroll
  for (int g = 0; g < 2; ++g) {
    const u16* qp = Q + base + (size_t)(q0 + w * 32 + g * 16 + l15) * HD + l4 * 8;
#pragma unroll
    for (int kf = 0; kf < 4; ++kf) qf[g][kf] = *(const bf16x8*)(qp + kf * 32);
  }

  float m_r[2] = {-1e30f, -1e30f}, l_r[2] = {0.f, 0.f};
  f32x4 accO[2][8];
#pragma unroll
  for (int g = 0; g < 2; ++g)
#pragma unroll
    for (int df = 0; df < 8; ++df)
#pragma unroll
      for (int q = 0; q < 4; ++q) accO[g][df][q] = 0.f;

  auto stageK = [&](int buf, int t0) {
    const u16* kb = K + base + (size_t)t0 * HD;
    char* kt = smem + buf * 16384;
#pragma unroll
    for (int i = 0; i < 4; ++i) {
      int c = w * 4 + i;
      int o = c * 1024 + lane * 16;
      int lo = o ^ (((o >> 8) & 7) << 4);
      gload_lds16(kb + (lo >> 1), kt + c * 1024);
    }
  };
  auto loadV = [&](int t0, bf16x8* vr) {
    const u16* vp = V + base + (size_t)(t0 + lane) * HD + w * 32;
#pragma unroll
    for (int i = 0; i < 4; ++i) vr[i] = *(const bf16x8*)(vp + i * 8);
  };
  auto writeV = [&](int buf, const bf16x8* vr) {
    u16* vt = (u16*)(smem + 32768 + buf * 18432);
#pragma unroll
    for (int i = 0; i < 4; ++i)
#pragma unroll
      for (int jj = 0; jj < 8; ++jj)
        vt[(w * 32 + i * 8 + jj) * 72 + lane] = (u16)vr[i][jj];
  };

  const int src0 = l15 + 32 * (l4 & 1);
  const int src1 = src0 + 16;
  const int half = l4 >> 1;
  union U8 { u32 u[4]; bf16x8 v; };

  bf16x8 vreg[4];
  stageK(0, 0);
  loadV(0, vreg);
  writeV(0, vreg);
  __syncthreads();

  for (int t = 0; t < nt; ++t) {
    const int cur = t & 1;
    const int t0 = t * 64;
    const bool pre = (t + 1 < nt);
    if (pre) { stageK(cur ^ 1, t0 + 64); loadV(t0 + 64, vreg); }

    const char* kt = smem + cur * 16384;
    const u16* vt = (const u16*)(smem + 32768 + cur * 18432);

    // S^T = K Q^T: lane holds S[kv = cf*16 + l4*4 + j][q = l15] per group
    f32x4 s[2][4];
#pragma unroll
    for (int cf = 0; cf < 4; ++cf) {
#pragma unroll
      for (int q = 0; q < 4; ++q) { s[0][cf][q] = 0.f; s[1][cf][q] = 0.f; }
      int row = cf * 16 + l15;
      int sw = (row & 7) << 4;
#pragma unroll
      for (int kf = 0; kf < 4; ++kf) {
        int off = (row * 256 + kf * 64 + l4 * 16) ^ sw;
        bf16x8 kfrag = *(const bf16x8*)(kt + off);
        s[0][cf] = __builtin_amdgcn_mfma_f32_16x16x32_bf16(kfrag, qf[0][kf], s[0][cf], 0, 0, 0);
        s[1][cf] = __builtin_amdgcn_mfma_f32_16x16x32_bf16(kfrag, qf[1][kf], s[1][cf], 0, 0, 0);
      }
    }

    u32 pk[2][4][2];
#pragma unroll
    for (int g = 0; g < 2; ++g) {
      const int qbase = q0 + w * 32 + g * 16;
      if (t0 + 63 > qbase) {  // diagonal: causal mask
        const int qg = qbase + l15;
#pragma unroll
        for (int cf = 0; cf < 4; ++cf)
#pragma unroll
          for (int j = 0; j < 4; ++j) {
            int kvg = t0 + cf * 16 + l4 * 4 + j;
            if (kvg > qg) s[g][cf][j] = -1e30f;
          }
      }
      // per-q max: in-lane 16 + cross-group reduce
      float pmax = s[g][0][0];
#pragma unroll
      for (int cf = 0; cf < 4; ++cf)
#pragma unroll
        for (int j = 0; j < 4; ++j) pmax = fmaxf(pmax, s[g][cf][j]);
      pmax = fmaxf(pmax, __shfl_xor(pmax, 16));
      pmax = fmaxf(pmax, __shfl_xor(pmax, 32));

      if (!__all(pmax <= m_r[g] + 8.f)) {  // T13 defer-max
        float mn = fmaxf(m_r[g], pmax);
        float rs = __expf(m_r[g] - mn);
        m_r[g] = mn;
        l_r[g] *= rs;
#pragma unroll
        for (int df = 0; df < 8; ++df)
#pragma unroll
          for (int j = 0; j < 4; ++j) accO[g][df][j] *= rs;
      }

      float ps = 0.f;
#pragma unroll
      for (int cf = 0; cf < 4; ++cf) {
        float p0 = __expf(s[g][cf][0] - m_r[g]);
        float p1 = __expf(s[g][cf][1] - m_r[g]);
        float p2 = __expf(s[g][cf][2] - m_r[g]);
        float p3 = __expf(s[g][cf][3] - m_r[g]);
        ps += (p0 + p1) + (p2 + p3);
        pk[g][cf][0] = cvtpk(p0, p1);
        pk[g][cf][1] = cvtpk(p2, p3);
      }
      ps += __shfl_xor(ps, 16);
      ps += __shfl_xor(ps, 32);
      l_r[g] += ps;
    }

    // PV: O^T += V^T P^T ; V^T frags shared across both q-groups
#pragma unroll
    for (int c = 0; c < 2; ++c) {
      const int c2 = 2 * c;
      U8 pu[2];
#pragma unroll
      for (int g = 0; g < 2; ++g) {
        u32 a0 = (u32)__shfl((int)pk[g][c2][0], src0);
        u32 b0 = (u32)__shfl((int)pk[g][c2 + 1][0], src0);
        u32 a1 = (u32)__shfl((int)pk[g][c2][1], src0);
        u32 b1 = (u32)__shfl((int)pk[g][c2 + 1][1], src0);
        u32 a2 = (u32)__shfl((int)pk[g][c2][0], src1);
        u32 b2 = (u32)__shfl((int)pk[g][c2 + 1][0], src1);
        u32 a3 = (u32)__shfl((int)pk[g][c2][1], src1);
        u32 b3 = (u32)__shfl((int)pk[g][c2 + 1][1], src1);
        pu[g].u[0] = half ? b0 : a0;
        pu[g].u[1] = half ? b1 : a1;
        pu[g].u[2] = half ? b2 : a2;
        pu[g].u[3] = half ? b3 : a3;
      }
#pragma unroll
      for (int df = 0; df < 8; ++df) {
        bf16x8 vf = *(const bf16x8*)(vt + (df * 16 + l15) * 72 + c * 32 + l4 * 8);
        accO[0][df] = __builtin_amdgcn_mfma_f32_16x16x32_bf16(vf, pu[0].v, accO[0][df], 0, 0, 0);
        accO[1][df] = __builtin_amdgcn_mfma_f32_16x16x32_bf16(vf, pu[1].v, accO[1][df], 0, 0, 0);
      }
    }

    if (pre) writeV(cur ^ 1, vreg);  // T14: write-late after PV
    __syncthreads();
  }

  // epilogue: divide, transpose O^T -> O via per-wave LDS, coalesced store
  float* Obuf = (float*)(smem + w * 8448);  // 16 x 132 f32, wave-private
  const int l31 = lane & 31;
#pragma unroll
  for (int g = 0; g < 2; ++g) {
    float inv = 1.f / l_r[g];
#pragma unroll
    for (int df = 0; df < 8; ++df) {
      f32x4 v = accO[g][df];
#pragma unroll
      for (int j = 0; j < 4; ++j) v[j] *= inv;
      *(f32x4*)&Obuf[l15 * 132 + df * 16 + l4 * 4] = v;
    }
#pragma unroll
    for (int p = 0; p < 8; ++p) {
      int row = p * 2 + (lane >> 5);
      f32x4 v = *(const f32x4*)&Obuf[row * 132 + l31 * 4];
      int qg = q0 + w * 32 + g * 16 + row;
      *(f32x4*)&Out[(size_t)(bb * N_ + qg) * D_ + h * HD + l31 * 4] = v;
    }
  }
}

extern "C" void kernel_launch(void* const* d_in, const int* in_sizes, int n_in,
                              void* d_out, int out_size, void* d_ws, size_t ws_size,
                              hipStream_t stream) {
  const float* x  = (const float*)d_in[0];
  const float* Wq = (const float*)d_in[1];
  const float* bq = (const float*)d_in[2];
  float* out = (float*)d_out;
  char* ws = (char*)d_ws;

  u16* Qb  = (u16*)(ws);
  u16* Kb  = (u16*)(ws + 16777216);
  u16* Vb  = (u16*)(ws + 2 * 16777216);
  u16* Xb  = (u16*)(ws + 3 * 16777216);
  u16* Wb  = (u16*)(ws + 4 * 16777216);
  float* tbl = (float*)(ws + 4 * 16777216 + 25165824);

  cvt_kernel<<<2048, 256, 0, stream>>>(x, Xb, (B_ * N_ * D_) / 4);
  cvt_kernel<<<2048, 256, 0, stream>>>(Wq, Wb, (3 * D_ * D_) / 4);
  rope_tbl_kernel<<<(N_ * 32 + 255) / 256, 256, 0, stream>>>(tbl);
  qkv_gemm_kernel<<<dim3(48, 32), 256, 0, stream>>>(Xb, Wb, bq, tbl, Qb, Kb, Vb);
  flash_kernel<<<512, 256, 0, stream>>>(Qb, Kb, Vb, out);
}

// Round 5
// 255.390 us; speedup vs baseline: 1.4656x; 1.0366x over previous
//
#include <hip/hip_runtime.h>
#include <hip/hip_bf16.h>
#include <math.h>

typedef unsigned short u16;
typedef unsigned int u32;
typedef __attribute__((ext_vector_type(8))) short bf16x8;
typedef __attribute__((ext_vector_type(4))) float f32x4;

#define B_ 2
#define N_ 2048
#define D_ 2048
#define H_ 16
#define HD 128
#define GK 2048

__device__ __forceinline__ u16 f2bf(float f) {
  u32 u = __float_as_uint(f);
  u = (u + 0x7fffu + ((u >> 16) & 1u)) >> 16;  // RNE
  return (u16)u;
}

__device__ __forceinline__ u32 cvtpk(float lo, float hi) {
  u32 r;
  asm("v_cvt_pk_bf16_f32 %0, %1, %2" : "=v"(r) : "v"(lo), "v"(hi));
  return r;
}

__device__ __forceinline__ void gload_lds16(const void* g, void* l) {
  __builtin_amdgcn_global_load_lds(
      (const __attribute__((address_space(1))) u32*)g,
      (__attribute__((address_space(3))) u32*)l, 16, 0, 0);
}

// ---------------- fp32 -> bf16 convert ----------------
__global__ __launch_bounds__(256) void cvt_kernel(const float* __restrict__ in,
                                                  u16* __restrict__ out, int n4) {
  int i = blockIdx.x * blockDim.x + threadIdx.x;
  int st = gridDim.x * blockDim.x;
  for (; i < n4; i += st) {
    float4 v = ((const float4*)in)[i];
    ushort4 o;
    o.x = f2bf(v.x); o.y = f2bf(v.y); o.z = f2bf(v.z); o.w = f2bf(v.w);
    ((ushort4*)out)[i] = o;
  }
}

// ---------------- RoPE cos/sin table: [pos][32] pairs ----------------
__global__ __launch_bounds__(256) void rope_tbl_kernel(float* __restrict__ tbl) {
  int i = blockIdx.x * blockDim.x + threadIdx.x;
  if (i >= N_ * 32) return;
  int pos = i >> 5, p = i & 31;
  double inv = pow(10000.0, -(double)p / 32.0);
  double a = (double)pos * inv;
  tbl[2 * i]     = (float)cos(a);
  tbl[2 * i + 1] = (float)sin(a);
}

// ---------------- QKV GEMM: 256x192 tile, BK=64, 8-phase-style schedule ----
// 8 waves (2M x 4N), per-wave 128x48. LDS 112KB: 2 bufs x (A 32KB + B 24KB).
// Counted vmcnt(4) once per K-tile (T4); stages run ~1.5 tiles ahead:
//   tile X's A0/A1 issue in phases 3/4 of segment X-2 (buffer reads done by
//   phase-2 post-MFMA barrier), B chunks in phases 1/2 of segment X-1.
// Raw s_barrier (no __syncthreads -> no vmcnt(0) drain), setprio on MFMA.
__global__ __launch_bounds__(512, 2) void qkv_gemm_kernel(
    const u16* __restrict__ X, const u16* __restrict__ W,
    const float* __restrict__ bias, const float* __restrict__ tbl,
    u16* __restrict__ Qo, u16* __restrict__ Ko, u16* __restrict__ Vo) {
  __shared__ char smem[114688];
  const int tid = threadIdx.x;
  const int lane = tid & 63;
  const int w = tid >> 6;            // 0..7
  const int wm = w >> 2, wn = w & 3; // 2M x 4N waves
  const int l15 = lane & 15, l4 = lane >> 4;

  // bijective XCD-chunk swizzle: 512 wgs, 8 XCDs, 64 contiguous per XCD
  const int bid = blockIdx.x;
  const int wg = (bid & 7) * 64 + (bid >> 3);
  const int n0 = (wg & 31) * 192;
  const int m0 = (wg >> 5) * 256;

  f32x4 acc[8][3];
#pragma unroll
  for (int fm = 0; fm < 8; ++fm)
#pragma unroll
    for (int fn = 0; fn < 3; ++fn)
#pragma unroll
      for (int q = 0; q < 4; ++q) acc[fm][fn][q] = 0.f;

  // cb buffer base = cb*57344; A region 32KB (2 halves of 16KB), B at +32768
  auto stageA = [&](int cb, int half, int k0) {
    char* dst = smem + cb * 57344 + half * 16384;
    const u16* src = X + (size_t)(m0 + half * 128) * GK + k0;
#pragma unroll
    for (int p = 0; p < 2; ++p) {
      int o = (w * 2 + p) * 1024 + lane * 16;
      int lo = o ^ (((o >> 7) & 7) << 4);
      gload_lds16(src + (size_t)(lo >> 7) * GK + ((lo & 127) >> 1),
                  dst + (w * 2 + p) * 1024);
    }
  };
  auto stageB = [&](int cb, int chunk, int k0) {
    char* dst = smem + cb * 57344 + 32768 + chunk * 8192;
    const u16* src = W + (size_t)(n0 + chunk * 64) * GK + k0;
    int o = w * 1024 + lane * 16;
    int lo = o ^ (((o >> 7) & 7) << 4);
    gload_lds16(src + (size_t)(lo >> 7) * GK + ((lo & 127) >> 1), dst + w * 1024);
  };

  const int NK = GK / 64;  // 32

  // prologue: tile0 full (7 loads) + tile1 A (4 loads); wait tile0, keep 4 in flight
  stageA(0, 0, 0); stageA(0, 1, 0);
  stageB(0, 0, 0); stageB(0, 1, 0); stageB(0, 2, 0);
  stageA(1, 0, 64); stageA(1, 1, 64);
  asm volatile("s_waitcnt vmcnt(4)" ::: "memory");
  __builtin_amdgcn_s_barrier();

  auto segment = [&](int T, int cb) {
    const char* Ab = smem + cb * 57344 + wm * 16384;
    const char* Bb = smem + cb * 57344 + 32768;
    const int kn1 = (T + 1) * 64, kn2 = (T + 2) * 64;
    bf16x8 a0[8], a1[8], b0[3], b1[3];

    // ---- phase 1: read k-half 0; stage T+1.B chunks 0,1; MFMA m0-3 x k0
#pragma unroll
    for (int fm = 0; fm < 8; ++fm) {
      int r = fm * 16 + l15;
      a0[fm] = *(const bf16x8*)(Ab + ((r * 128 + l4 * 16) ^ ((r & 7) << 4)));
    }
#pragma unroll
    for (int fn = 0; fn < 3; ++fn) {
      int r = wn * 48 + fn * 16 + l15;
      b0[fn] = *(const bf16x8*)(Bb + ((r * 128 + l4 * 16) ^ ((r & 7) << 4)));
    }
    if (T + 1 < NK) { stageB(cb ^ 1, 0, kn1); stageB(cb ^ 1, 1, kn1); }
    __builtin_amdgcn_s_barrier();
    __builtin_amdgcn_s_setprio(1);
#pragma unroll
    for (int fm = 0; fm < 4; ++fm)
#pragma unroll
      for (int fn = 0; fn < 3; ++fn)
        acc[fm][fn] = __builtin_amdgcn_mfma_f32_16x16x32_bf16(a0[fm], b0[fn], acc[fm][fn], 0, 0, 0);
    __builtin_amdgcn_s_setprio(0);
    __builtin_amdgcn_s_barrier();

    // ---- phase 2: read k-half 1; stage T+1.B chunk 2; MFMA m4-7 x k0
#pragma unroll
    for (int fm = 0; fm < 8; ++fm) {
      int r = fm * 16 + l15;
      a1[fm] = *(const bf16x8*)(Ab + ((r * 128 + 64 + l4 * 16) ^ ((r & 7) << 4)));
    }
#pragma unroll
    for (int fn = 0; fn < 3; ++fn) {
      int r = wn * 48 + fn * 16 + l15;
      b1[fn] = *(const bf16x8*)(Bb + ((r * 128 + 64 + l4 * 16) ^ ((r & 7) << 4)));
    }
    if (T + 1 < NK) stageB(cb ^ 1, 2, kn1);
    __builtin_amdgcn_s_barrier();
    __builtin_amdgcn_s_setprio(1);
#pragma unroll
    for (int fm = 4; fm < 8; ++fm)
#pragma unroll
      for (int fn = 0; fn < 3; ++fn)
        acc[fm][fn] = __builtin_amdgcn_mfma_f32_16x16x32_bf16(a0[fm], b0[fn], acc[fm][fn], 0, 0, 0);
    __builtin_amdgcn_s_setprio(0);
    __builtin_amdgcn_s_barrier();
    // all reads of buf cb complete block-wide here -> safe to re-stage it

    // ---- phase 3: stage T+2.A0 into buf cb; MFMA m0-3 x k1
    asm volatile("" ::: "memory");  // fence: no ds_read may sink past re-stage
    if (T + 2 < NK) stageA(cb, 0, kn2);
    __builtin_amdgcn_s_barrier();
    __builtin_amdgcn_s_setprio(1);
#pragma unroll
    for (int fm = 0; fm < 4; ++fm)
#pragma unroll
      for (int fn = 0; fn < 3; ++fn)
        acc[fm][fn] = __builtin_amdgcn_mfma_f32_16x16x32_bf16(a1[fm], b1[fn], acc[fm][fn], 0, 0, 0);
    __builtin_amdgcn_s_setprio(0);
    __builtin_amdgcn_s_barrier();

    // ---- phase 4: stage T+2.A1; counted vmcnt; MFMA m4-7 x k1
    asm volatile("" ::: "memory");
    if (T + 2 < NK) {
      stageA(cb, 1, kn2);
      asm volatile("s_waitcnt vmcnt(4)" ::: "memory");  // tile T+1 landed; T+2.A in flight
    } else {
      asm volatile("s_waitcnt vmcnt(0)" ::: "memory");  // tail drain
    }
    __builtin_amdgcn_s_barrier();
    __builtin_amdgcn_s_setprio(1);
#pragma unroll
    for (int fm = 4; fm < 8; ++fm)
#pragma unroll
      for (int fn = 0; fn < 3; ++fn)
        acc[fm][fn] = __builtin_amdgcn_mfma_f32_16x16x32_bf16(a1[fm], b1[fn], acc[fm][fn], 0, 0, 0);
    __builtin_amdgcn_s_setprio(0);
    __builtin_amdgcn_s_barrier();
  };

  for (int T = 0; T < NK; T += 2) { segment(T, 0); segment(T + 1, 1); }

  // epilogue: bias + RoPE (q,k sections, d<64) + scatter; Q pre-scaled
  const float QSCALE = 0.08838834764831845f;  // 1/sqrt(128)
#pragma unroll
  for (int fn = 0; fn < 3; ++fn) {
    int gn = n0 + wn * 48 + fn * 16 + l15;
    float bv = bias[gn];
    int sec = gn >> 11;
    int wi = gn & 2047;
    int h = wi >> 7;
    int d = wi & 127;
    u16* dstbase = (sec == 0) ? Qo : (sec == 1) ? Ko : Vo;
    float mulf = (sec == 0) ? QSCALE : 1.f;
    bool doRope = (sec < 2) && (d < 64);
    int pidx = d >> 1;
    bool odd = (d & 1) != 0;
#pragma unroll
    for (int fm = 0; fm < 8; ++fm) {
#pragma unroll
      for (int j = 0; j < 4; ++j) {
        int gm = m0 + wm * 128 + fm * 16 + l4 * 4 + j;
        int bb = gm >> 11;
        int pos = gm & 2047;
        float v = acc[fm][fn][j] + bv;
        float pr = __shfl_xor(v, 1);
        float ov = v;
        if (doRope) {
          float2 cs = ((const float2*)tbl)[pos * 32 + pidx];
          ov = odd ? (v * cs.x + pr * cs.y) : (v * cs.x - pr * cs.y);
        }
        dstbase[(size_t)((bb * H_ + h) * N_ + pos) * HD + d] = f2bf(ov * mulf);
      }
    }
  }
}

// ---------------- causal flash attention ----------------
// 512 blocks (1-D), 4 waves x 32 q-rows = 128 q-rows/block. KVBLK=64,
// double-buffered K/V, one barrier/tile, T14 staged V, defer-max softmax.
// LPT dispatch (longest tiles first) + XCD-chunked bh mapping for L2.
__global__ __launch_bounds__(256, 2) void flash_kernel(
    const u16* __restrict__ Q, const u16* __restrict__ K, const u16* __restrict__ V,
    float* __restrict__ Out) {
  __shared__ char smem[69632];  // K dbuf 2x16KB | V dbuf 2x18KB

  const int tid = threadIdx.x, lane = tid & 63, w = tid >> 6;
  const int l15 = lane & 15, l4 = lane >> 4;

  const int bid = blockIdx.x;
  const int xcd = bid & 7, slot = bid >> 3;
  const int bh = xcd * 4 + (slot >> 4);   // 4 bh per XCD -> K/V fits 4MB L2
  const int x = 15 - (slot & 15);         // LPT: longest q-tiles dispatch first
  const int bb = bh >> 4, h = bh & 15;
  const size_t base = (size_t)bh * (N_ * HD);
  const int q0 = x * 128;
  const int nt = 2 * x + 2;

  // Q B-frags for two 16-row groups (col q = l15, k rows d = kf*32 + l4*8)
  bf16x8 qf[2][4];
#pragma unroll
  for (int g = 0; g < 2; ++g) {
    const u16* qp = Q + base + (size_t)(q0 + w * 32 + g * 16 + l15) * HD + l4 * 8;
#pragma unroll
    for (int kf = 0; kf < 4; ++kf) qf[g][kf] = *(const bf16x8*)(qp + kf * 32);
  }

  float m_r[2] = {-1e30f, -1e30f}, l_r[2] = {0.f, 0.f};
  f32x4 accO[2][8];
#pragma unroll
  for (int g = 0; g < 2; ++g)
#pragma unroll
    for (int df = 0; df < 8; ++df)
#pragma unroll
      for (int q = 0; q < 4; ++q) accO[g][df][q] = 0.f;

  auto stageK = [&](int buf, int t0) {
    const u16* kb = K + base + (size_t)t0 * HD;
    char* kt = smem + buf * 16384;
#pragma unroll
    for (int i = 0; i < 4; ++i) {
      int c = w * 4 + i;
      int o = c * 1024 + lane * 16;
      int lo = o ^ (((o >> 8) & 7) << 4);
      gload_lds16(kb + (lo >> 1), kt + c * 1024);
    }
  };
  auto loadV = [&](int t0, bf16x8* vr) {
    const u16* vp = V + base + (size_t)(t0 + lane) * HD + w * 32;
#pragma unroll
    for (int i = 0; i < 4; ++i) vr[i] = *(const bf16x8*)(vp + i * 8);
  };
  auto writeV = [&](int buf, const bf16x8* vr) {
    u16* vt = (u16*)(smem + 32768 + buf * 18432);
#pragma unroll
    for (int i = 0; i < 4; ++i)
#pragma unroll
      for (int jj = 0; jj < 8; ++jj)
        vt[(w * 32 + i * 8 + jj) * 72 + lane] = (u16)vr[i][jj];
  };

  const int src0 = l15 + 32 * (l4 & 1);
  const int src1 = src0 + 16;
  const int half = l4 >> 1;
  union U8 { u32 u[4]; bf16x8 v; };

  bf16x8 vreg[4];
  stageK(0, 0);
  loadV(0, vreg);
  writeV(0, vreg);
  __syncthreads();

  for (int t = 0; t < nt; ++t) {
    const int cur = t & 1;
    const int t0 = t * 64;
    const bool pre = (t + 1 < nt);
    if (pre) { stageK(cur ^ 1, t0 + 64); loadV(t0 + 64, vreg); }

    const char* kt = smem + cur * 16384;
    const u16* vt = (const u16*)(smem + 32768 + cur * 18432);

    // S^T = K Q^T: lane holds S[kv = cf*16 + l4*4 + j][q = l15] per group
    f32x4 s[2][4];
#pragma unroll
    for (int cf = 0; cf < 4; ++cf) {
#pragma unroll
      for (int q = 0; q < 4; ++q) { s[0][cf][q] = 0.f; s[1][cf][q] = 0.f; }
      int row = cf * 16 + l15;
      int sw = (row & 7) << 4;
#pragma unroll
      for (int kf = 0; kf < 4; ++kf) {
        int off = (row * 256 + kf * 64 + l4 * 16) ^ sw;
        bf16x8 kfrag = *(const bf16x8*)(kt + off);
        s[0][cf] = __builtin_amdgcn_mfma_f32_16x16x32_bf16(kfrag, qf[0][kf], s[0][cf], 0, 0, 0);
        s[1][cf] = __builtin_amdgcn_mfma_f32_16x16x32_bf16(kfrag, qf[1][kf], s[1][cf], 0, 0, 0);
      }
    }

    u32 pk[2][4][2];
#pragma unroll
    for (int g = 0; g < 2; ++g) {
      const int qbase = q0 + w * 32 + g * 16;
      if (t0 + 63 > qbase) {  // diagonal: causal mask
        const int qg = qbase + l15;
#pragma unroll
        for (int cf = 0; cf < 4; ++cf)
#pragma unroll
          for (int j = 0; j < 4; ++j) {
            int kvg = t0 + cf * 16 + l4 * 4 + j;
            if (kvg > qg) s[g][cf][j] = -1e30f;
          }
      }
      // per-q max: in-lane 16 + cross-group reduce
      float pmax = s[g][0][0];
#pragma unroll
      for (int cf = 0; cf < 4; ++cf)
#pragma unroll
        for (int j = 0; j < 4; ++j) pmax = fmaxf(pmax, s[g][cf][j]);
      pmax = fmaxf(pmax, __shfl_xor(pmax, 16));
      pmax = fmaxf(pmax, __shfl_xor(pmax, 32));

      if (!__all(pmax <= m_r[g] + 8.f)) {  // T13 defer-max
        float mn = fmaxf(m_r[g], pmax);
        float rs = __expf(m_r[g] - mn);
        m_r[g] = mn;
        l_r[g] *= rs;
#pragma unroll
        for (int df = 0; df < 8; ++df)
#pragma unroll
          for (int j = 0; j < 4; ++j) accO[g][df][j] *= rs;
      }

      float ps = 0.f;
#pragma unroll
      for (int cf = 0; cf < 4; ++cf) {
        float p0 = __expf(s[g][cf][0] - m_r[g]);
        float p1 = __expf(s[g][cf][1] - m_r[g]);
        float p2 = __expf(s[g][cf][2] - m_r[g]);
        float p3 = __expf(s[g][cf][3] - m_r[g]);
        ps += (p0 + p1) + (p2 + p3);
        pk[g][cf][0] = cvtpk(p0, p1);
        pk[g][cf][1] = cvtpk(p2, p3);
      }
      ps += __shfl_xor(ps, 16);
      ps += __shfl_xor(ps, 32);
      l_r[g] += ps;
    }

    // PV: O^T += V^T P^T ; V^T frags shared across both q-groups
#pragma unroll
    for (int c = 0; c < 2; ++c) {
      const int c2 = 2 * c;
      U8 pu[2];
#pragma unroll
      for (int g = 0; g < 2; ++g) {
        u32 a0 = (u32)__shfl((int)pk[g][c2][0], src0);
        u32 b0 = (u32)__shfl((int)pk[g][c2 + 1][0], src0);
        u32 a1 = (u32)__shfl((int)pk[g][c2][1], src0);
        u32 b1 = (u32)__shfl((int)pk[g][c2 + 1][1], src0);
        u32 a2 = (u32)__shfl((int)pk[g][c2][0], src1);
        u32 b2 = (u32)__shfl((int)pk[g][c2 + 1][0], src1);
        u32 a3 = (u32)__shfl((int)pk[g][c2][1], src1);
        u32 b3 = (u32)__shfl((int)pk[g][c2 + 1][1], src1);
        pu[g].u[0] = half ? b0 : a0;
        pu[g].u[1] = half ? b1 : a1;
        pu[g].u[2] = half ? b2 : a2;
        pu[g].u[3] = half ? b3 : a3;
      }
#pragma unroll
      for (int df = 0; df < 8; ++df) {
        bf16x8 vf = *(const bf16x8*)(vt + (df * 16 + l15) * 72 + c * 32 + l4 * 8);
        accO[0][df] = __builtin_amdgcn_mfma_f32_16x16x32_bf16(vf, pu[0].v, accO[0][df], 0, 0, 0);
        accO[1][df] = __builtin_amdgcn_mfma_f32_16x16x32_bf16(vf, pu[1].v, accO[1][df], 0, 0, 0);
      }
    }

    if (pre) writeV(cur ^ 1, vreg);  // T14: write-late after PV
    __syncthreads();
  }

  // epilogue: divide, transpose O^T -> O via per-wave LDS, coalesced store
  float* Obuf = (float*)(smem + w * 8448);  // 16 x 132 f32, wave-private
  const int l31 = lane & 31;
#pragma unroll
  for (int g = 0; g < 2; ++g) {
    float inv = 1.f / l_r[g];
#pragma unroll
    for (int df = 0; df < 8; ++df) {
      f32x4 v = accO[g][df];
#pragma unroll
      for (int j = 0; j < 4; ++j) v[j] *= inv;
      *(f32x4*)&Obuf[l15 * 132 + df * 16 + l4 * 4] = v;
    }
#pragma unroll
    for (int p = 0; p < 8; ++p) {
      int row = p * 2 + (lane >> 5);
      f32x4 v = *(const f32x4*)&Obuf[row * 132 + l31 * 4];
      int qg = q0 + w * 32 + g * 16 + row;
      *(f32x4*)&Out[(size_t)(bb * N_ + qg) * D_ + h * HD + l31 * 4] = v;
    }
  }
}

extern "C" void kernel_launch(void* const* d_in, const int* in_sizes, int n_in,
                              void* d_out, int out_size, void* d_ws, size_t ws_size,
                              hipStream_t stream) {
  const float* x  = (const float*)d_in[0];
  const float* Wq = (const float*)d_in[1];
  const float* bq = (const float*)d_in[2];
  float* out = (float*)d_out;
  char* ws = (char*)d_ws;

  u16* Qb  = (u16*)(ws);
  u16* Kb  = (u16*)(ws + 16777216);
  u16* Vb  = (u16*)(ws + 2 * 16777216);
  u16* Xb  = (u16*)(ws + 3 * 16777216);
  u16* Wb  = (u16*)(ws + 4 * 16777216);
  float* tbl = (float*)(ws + 4 * 16777216 + 25165824);

  cvt_kernel<<<2048, 256, 0, stream>>>(x, Xb, (B_ * N_ * D_) / 4);
  cvt_kernel<<<2048, 256, 0, stream>>>(Wq, Wb, (3 * D_ * D_) / 4);
  rope_tbl_kernel<<<(N_ * 32 + 255) / 256, 256, 0, stream>>>(tbl);
  qkv_gemm_kernel<<<512, 512, 0, stream>>>(Xb, Wb, bq, tbl, Qb, Kb, Vb);
  flash_kernel<<<512, 256, 0, stream>>>(Qb, Kb, Vb, out);
}

// Round 6
// 254.453 us; speedup vs baseline: 1.4710x; 1.0037x over previous
//
#include <hip/hip_runtime.h>
#include <hip/hip_bf16.h>
#include <math.h>

typedef unsigned short u16;
typedef unsigned int u32;
typedef __attribute__((ext_vector_type(8))) short bf16x8;
typedef __attribute__((ext_vector_type(4))) float f32x4;

#define B_ 2
#define N_ 2048
#define D_ 2048
#define H_ 16
#define HD 128
#define GK 2048

__device__ __forceinline__ u16 f2bf(float f) {
  u32 u = __float_as_uint(f);
  u = (u + 0x7fffu + ((u >> 16) & 1u)) >> 16;  // RNE
  return (u16)u;
}

__device__ __forceinline__ u32 cvtpk(float lo, float hi) {
  u32 r;
  asm("v_cvt_pk_bf16_f32 %0, %1, %2" : "=v"(r) : "v"(lo), "v"(hi));
  return r;
}

__device__ __forceinline__ void gload_lds16(const void* g, void* l) {
  __builtin_amdgcn_global_load_lds(
      (const __attribute__((address_space(1))) u32*)g,
      (__attribute__((address_space(3))) u32*)l, 16, 0, 0);
}

// ---------------- fp32 -> bf16 convert ----------------
__global__ __launch_bounds__(256) void cvt_kernel(const float* __restrict__ in,
                                                  u16* __restrict__ out, int n4) {
  int i = blockIdx.x * blockDim.x + threadIdx.x;
  int st = gridDim.x * blockDim.x;
  for (; i < n4; i += st) {
    float4 v = ((const float4*)in)[i];
    ushort4 o;
    o.x = f2bf(v.x); o.y = f2bf(v.y); o.z = f2bf(v.z); o.w = f2bf(v.w);
    ((ushort4*)out)[i] = o;
  }
}

// ---------------- RoPE cos/sin table: [pos][32] pairs ----------------
__global__ __launch_bounds__(256) void rope_tbl_kernel(float* __restrict__ tbl) {
  int i = blockIdx.x * blockDim.x + threadIdx.x;
  if (i >= N_ * 32) return;
  int pos = i >> 5, p = i & 31;
  double inv = pow(10000.0, -(double)p / 32.0);
  double a = (double)pos * inv;
  tbl[2 * i]     = (float)cos(a);
  tbl[2 * i + 1] = (float)sin(a);
}

// ---------------- QKV GEMM: 256x192 tile, BK=64 ----------------
// 8 waves (2M x 4N), per-wave 128x48. LDS 144KB: A tri-buf 3x32KB (A(T+2)
// stages into a buffer nobody reads this tile -> reads spread evenly),
// B dbuf 2x24KB. 4 phases/K-tile, each {quadrant ds_reads || 1-2 gloads ||
// barrier || setprio 12 MFMA || barrier}; counted vmcnt(4) once per tile.
__global__ __launch_bounds__(512, 2) void qkv_gemm_kernel(
    const u16* __restrict__ X, const u16* __restrict__ W,
    const float* __restrict__ bias, const float* __restrict__ tbl,
    u16* __restrict__ Qo, u16* __restrict__ Ko, u16* __restrict__ Vo) {
  __shared__ char smem[147456];  // A: 3x32KB | B: 2x24KB at +98304
  const int tid = threadIdx.x;
  const int lane = tid & 63;
  const int w = tid >> 6;            // 0..7
  const int wm = w >> 2, wn = w & 3; // 2M x 4N waves
  const int l15 = lane & 15, l4 = lane >> 4;

  // bijective XCD-chunk swizzle: 512 wgs, 8 XCDs, 64 contiguous per XCD
  const int bid = blockIdx.x;
  const int wg = (bid & 7) * 64 + (bid >> 3);
  const int n0 = (wg & 31) * 192;
  const int m0 = (wg >> 5) * 256;

  // read-side swizzled in-row byte offsets (XOR may flip bit6 = k-half bit)
  const int aof0 = (l4 * 16) ^ ((l15 & 7) << 4);
  const int aof1 = (64 + l4 * 16) ^ ((l15 & 7) << 4);

  // stage-side precompute (inverse swizzle of per-thread chunk slot)
  int srowA[2], scolA[2];
#pragma unroll
  for (int p = 0; p < 2; ++p) {
    int o = (w * 2 + p) * 1024 + lane * 16;
    int lo = o ^ (((o >> 7) & 7) << 4);
    srowA[p] = lo >> 7;
    scolA[p] = (lo & 127) >> 1;
  }
  const int oB = w * 1024 + lane * 16;
  const int loB = oB ^ (((oB >> 7) & 7) << 4);
  const int srowB = loB >> 7, scolB = (loB & 127) >> 1;

  f32x4 acc[8][3];
#pragma unroll
  for (int fm = 0; fm < 8; ++fm)
#pragma unroll
    for (int fn = 0; fn < 3; ++fn)
#pragma unroll
      for (int q = 0; q < 4; ++q) acc[fm][fn][q] = 0.f;

  auto stageA = [&](char* Abase, int half, int k0) {
#pragma unroll
    for (int p = 0; p < 2; ++p) {
      gload_lds16(X + (size_t)(m0 + half * 128 + srowA[p]) * GK + k0 + scolA[p],
                  Abase + half * 16384 + (w * 2 + p) * 1024);
    }
  };
  auto stageB = [&](char* Bbase, int chunk, int k0) {
    gload_lds16(W + (size_t)(n0 + chunk * 64 + srowB) * GK + k0 + scolB,
                Bbase + chunk * 8192 + w * 1024);
  };

  const int NK = GK / 64;  // 32

  // prologue: A(0), B(0), A(1); wait first 7 landed, keep A(1)'s 4 in flight
  stageA(smem, 0, 0); stageA(smem, 1, 0);
  stageB(smem + 98304, 0, 0); stageB(smem + 98304, 1, 0); stageB(smem + 98304, 2, 0);
  stageA(smem + 32768, 0, 64); stageA(smem + 32768, 1, 64);
  asm volatile("s_waitcnt vmcnt(4)" ::: "memory");
  __builtin_amdgcn_s_barrier();

  int at = 0;  // A-buf holding tile T
  for (int T = 0; T < NK; ++T) {
    const int bt = T & 1;
    int an2 = at + 2; if (an2 >= 3) an2 -= 3;
    const char* Ab = smem + at * 32768 + wm * 16384;
    const char* Bb = smem + 98304 + bt * 24576;
    char* Bn = smem + 98304 + (bt ^ 1) * 24576;
    char* An = smem + an2 * 32768;
    const int kn1 = (T + 1) * 64, kn2 = (T + 2) * 64;
    const bool hasB = (T + 1 < NK), hasA = (T + 2 < NK);

    bf16x8 b[3], a[4];

    // ---- phase 0: k-half 0, m-quad 0
#pragma unroll
    for (int fn = 0; fn < 3; ++fn)
      b[fn] = *(const bf16x8*)(Bb + (wn * 48 + fn * 16 + l15) * 128 + aof0);
#pragma unroll
    for (int fm = 0; fm < 4; ++fm)
      a[fm] = *(const bf16x8*)(Ab + (fm * 16 + l15) * 128 + aof0);
    if (hasB) { stageB(Bn, 0, kn1); stageB(Bn, 1, kn1); }
    __builtin_amdgcn_s_barrier();
    __builtin_amdgcn_s_setprio(1);
#pragma unroll
    for (int fm = 0; fm < 4; ++fm)
#pragma unroll
      for (int fn = 0; fn < 3; ++fn)
        acc[fm][fn] = __builtin_amdgcn_mfma_f32_16x16x32_bf16(a[fm], b[fn], acc[fm][fn], 0, 0, 0);
    __builtin_amdgcn_s_setprio(0);
    __builtin_amdgcn_s_barrier();

    // ---- phase 1: k-half 0, m-quad 1
#pragma unroll
    for (int fm = 0; fm < 4; ++fm)
      a[fm] = *(const bf16x8*)(Ab + ((fm + 4) * 16 + l15) * 128 + aof0);
    if (hasB) stageB(Bn, 2, kn1);
    __builtin_amdgcn_s_barrier();
    __builtin_amdgcn_s_setprio(1);
#pragma unroll
    for (int fm = 0; fm < 4; ++fm)
#pragma unroll
      for (int fn = 0; fn < 3; ++fn)
        acc[fm + 4][fn] = __builtin_amdgcn_mfma_f32_16x16x32_bf16(a[fm], b[fn], acc[fm + 4][fn], 0, 0, 0);
    __builtin_amdgcn_s_setprio(0);
    __builtin_amdgcn_s_barrier();

    // ---- phase 2: k-half 1, m-quad 0 (stage A(T+2) -> third buffer)
#pragma unroll
    for (int fn = 0; fn < 3; ++fn)
      b[fn] = *(const bf16x8*)(Bb + (wn * 48 + fn * 16 + l15) * 128 + aof1);
#pragma unroll
    for (int fm = 0; fm < 4; ++fm)
      a[fm] = *(const bf16x8*)(Ab + (fm * 16 + l15) * 128 + aof1);
    if (hasA) stageA(An, 0, kn2);
    __builtin_amdgcn_s_barrier();
    __builtin_amdgcn_s_setprio(1);
#pragma unroll
    for (int fm = 0; fm < 4; ++fm)
#pragma unroll
      for (int fn = 0; fn < 3; ++fn)
        acc[fm][fn] = __builtin_amdgcn_mfma_f32_16x16x32_bf16(a[fm], b[fn], acc[fm][fn], 0, 0, 0);
    __builtin_amdgcn_s_setprio(0);
    __builtin_amdgcn_s_barrier();

    // ---- phase 3: k-half 1, m-quad 1; counted vmcnt once per tile
#pragma unroll
    for (int fm = 0; fm < 4; ++fm)
      a[fm] = *(const bf16x8*)(Ab + ((fm + 4) * 16 + l15) * 128 + aof1);
    if (hasA) {
      stageA(An, 1, kn2);
      asm volatile("s_waitcnt vmcnt(4)" ::: "memory");  // T+1 landed; T+2.A in flight
    } else {
      asm volatile("s_waitcnt vmcnt(0)" ::: "memory");  // tail drain
    }
    __builtin_amdgcn_s_barrier();
    __builtin_amdgcn_s_setprio(1);
#pragma unroll
    for (int fm = 0; fm < 4; ++fm)
#pragma unroll
      for (int fn = 0; fn < 3; ++fn)
        acc[fm + 4][fn] = __builtin_amdgcn_mfma_f32_16x16x32_bf16(a[fm], b[fn], acc[fm + 4][fn], 0, 0, 0);
    __builtin_amdgcn_s_setprio(0);
    __builtin_amdgcn_s_barrier();

    at = (at + 1 == 3) ? 0 : at + 1;
  }

  // epilogue: bias + RoPE (q,k sections, d<64) + scatter; Q pre-scaled
  const float QSCALE = 0.08838834764831845f;  // 1/sqrt(128)
#pragma unroll
  for (int fn = 0; fn < 3; ++fn) {
    int gn = n0 + wn * 48 + fn * 16 + l15;
    float bv = bias[gn];
    int sec = gn >> 11;
    int wi = gn & 2047;
    int h = wi >> 7;
    int d = wi & 127;
    u16* dstbase = (sec == 0) ? Qo : (sec == 1) ? Ko : Vo;
    float mulf = (sec == 0) ? QSCALE : 1.f;
    bool doRope = (sec < 2) && (d < 64);
    int pidx = d >> 1;
    bool odd = (d & 1) != 0;
#pragma unroll
    for (int fm = 0; fm < 8; ++fm) {
#pragma unroll
      for (int j = 0; j < 4; ++j) {
        int gm = m0 + wm * 128 + fm * 16 + l4 * 4 + j;
        int bb = gm >> 11;
        int pos = gm & 2047;
        float v = acc[fm][fn][j] + bv;
        float pr = __shfl_xor(v, 1);
        float ov = v;
        if (doRope) {
          float2 cs = ((const float2*)tbl)[pos * 32 + pidx];
          ov = odd ? (v * cs.x + pr * cs.y) : (v * cs.x - pr * cs.y);
        }
        dstbase[(size_t)((bb * H_ + h) * N_ + pos) * HD + d] = f2bf(ov * mulf);
      }
    }
  }
}

// ---------------- causal flash attention ----------------
// 512 blocks (1-D), 4 waves x 32 q-rows = 128 q-rows/block. KVBLK=64,
// double-buffered K/V, one barrier/tile, T14 staged V, defer-max softmax.
// LPT dispatch (longest tiles first) + XCD-chunked bh mapping for L2.
__global__ __launch_bounds__(256, 2) void flash_kernel(
    const u16* __restrict__ Q, const u16* __restrict__ K, const u16* __restrict__ V,
    float* __restrict__ Out) {
  __shared__ char smem[69632];  // K dbuf 2x16KB | V dbuf 2x18KB

  const int tid = threadIdx.x, lane = tid & 63, w = tid >> 6;
  const int l15 = lane & 15, l4 = lane >> 4;

  const int bid = blockIdx.x;
  const int xcd = bid & 7, slot = bid >> 3;
  const int bh = xcd * 4 + (slot >> 4);   // 4 bh per XCD -> K/V fits 4MB L2
  const int x = 15 - (slot & 15);         // LPT: longest q-tiles dispatch first
  const int bb = bh >> 4, h = bh & 15;
  const size_t base = (size_t)bh * (N_ * HD);
  const int q0 = x * 128;
  const int nt = 2 * x + 2;

  // Q B-frags for two 16-row groups (col q = l15, k rows d = kf*32 + l4*8)
  bf16x8 qf[2][4];
#pragma unroll
  for (int g = 0; g < 2; ++g) {
    const u16* qp = Q + base + (size_t)(q0 + w * 32 + g * 16 + l15) * HD + l4 * 8;
#pragma unroll
    for (int kf = 0; kf < 4; ++kf) qf[g][kf] = *(const bf16x8*)(qp + kf * 32);
  }

  float m_r[2] = {-1e30f, -1e30f}, l_r[2] = {0.f, 0.f};
  f32x4 accO[2][8];
#pragma unroll
  for (int g = 0; g < 2; ++g)
#pragma unroll
    for (int df = 0; df < 8; ++df)
#pragma unroll
      for (int q = 0; q < 4; ++q) accO[g][df][q] = 0.f;

  auto stageK = [&](int buf, int t0) {
    const u16* kb = K + base + (size_t)t0 * HD;
    char* kt = smem + buf * 16384;
#pragma unroll
    for (int i = 0; i < 4; ++i) {
      int c = w * 4 + i;
      int o = c * 1024 + lane * 16;
      int lo = o ^ (((o >> 8) & 7) << 4);
      gload_lds16(kb + (lo >> 1), kt + c * 1024);
    }
  };
  auto loadV = [&](int t0, bf16x8* vr) {
    const u16* vp = V + base + (size_t)(t0 + lane) * HD + w * 32;
#pragma unroll
    for (int i = 0; i < 4; ++i) vr[i] = *(const bf16x8*)(vp + i * 8);
  };
  auto writeV = [&](int buf, const bf16x8* vr) {
    u16* vt = (u16*)(smem + 32768 + buf * 18432);
#pragma unroll
    for (int i = 0; i < 4; ++i)
#pragma unroll
      for (int jj = 0; jj < 8; ++jj)
        vt[(w * 32 + i * 8 + jj) * 72 + lane] = (u16)vr[i][jj];
  };

  const int src0 = l15 + 32 * (l4 & 1);
  const int src1 = src0 + 16;
  const int half = l4 >> 1;
  union U8 { u32 u[4]; bf16x8 v; };

  bf16x8 vreg[4];
  stageK(0, 0);
  loadV(0, vreg);
  writeV(0, vreg);
  __syncthreads();

  for (int t = 0; t < nt; ++t) {
    const int cur = t & 1;
    const int t0 = t * 64;
    const bool pre = (t + 1 < nt);
    if (pre) { stageK(cur ^ 1, t0 + 64); loadV(t0 + 64, vreg); }

    const char* kt = smem + cur * 16384;
    const u16* vt = (const u16*)(smem + 32768 + cur * 18432);

    // S^T = K Q^T: lane holds S[kv = cf*16 + l4*4 + j][q = l15] per group
    f32x4 s[2][4];
#pragma unroll
    for (int cf = 0; cf < 4; ++cf) {
#pragma unroll
      for (int q = 0; q < 4; ++q) { s[0][cf][q] = 0.f; s[1][cf][q] = 0.f; }
      int row = cf * 16 + l15;
      int sw = (row & 7) << 4;
#pragma unroll
      for (int kf = 0; kf < 4; ++kf) {
        int off = (row * 256 + kf * 64 + l4 * 16) ^ sw;
        bf16x8 kfrag = *(const bf16x8*)(kt + off);
        s[0][cf] = __builtin_amdgcn_mfma_f32_16x16x32_bf16(kfrag, qf[0][kf], s[0][cf], 0, 0, 0);
        s[1][cf] = __builtin_amdgcn_mfma_f32_16x16x32_bf16(kfrag, qf[1][kf], s[1][cf], 0, 0, 0);
      }
    }

    u32 pk[2][4][2];
#pragma unroll
    for (int g = 0; g < 2; ++g) {
      const int qbase = q0 + w * 32 + g * 16;
      if (t0 + 63 > qbase) {  // diagonal: causal mask
        const int qg = qbase + l15;
#pragma unroll
        for (int cf = 0; cf < 4; ++cf)
#pragma unroll
          for (int j = 0; j < 4; ++j) {
            int kvg = t0 + cf * 16 + l4 * 4 + j;
            if (kvg > qg) s[g][cf][j] = -1e30f;
          }
      }
      // per-q max: in-lane 16 + cross-group reduce
      float pmax = s[g][0][0];
#pragma unroll
      for (int cf = 0; cf < 4; ++cf)
#pragma unroll
        for (int j = 0; j < 4; ++j) pmax = fmaxf(pmax, s[g][cf][j]);
      pmax = fmaxf(pmax, __shfl_xor(pmax, 16));
      pmax = fmaxf(pmax, __shfl_xor(pmax, 32));

      if (!__all(pmax <= m_r[g] + 8.f)) {  // T13 defer-max
        float mn = fmaxf(m_r[g], pmax);
        float rs = __expf(m_r[g] - mn);
        m_r[g] = mn;
        l_r[g] *= rs;
#pragma unroll
        for (int df = 0; df < 8; ++df)
#pragma unroll
          for (int j = 0; j < 4; ++j) accO[g][df][j] *= rs;
      }

      float ps = 0.f;
#pragma unroll
      for (int cf = 0; cf < 4; ++cf) {
        float p0 = __expf(s[g][cf][0] - m_r[g]);
        float p1 = __expf(s[g][cf][1] - m_r[g]);
        float p2 = __expf(s[g][cf][2] - m_r[g]);
        float p3 = __expf(s[g][cf][3] - m_r[g]);
        ps += (p0 + p1) + (p2 + p3);
        pk[g][cf][0] = cvtpk(p0, p1);
        pk[g][cf][1] = cvtpk(p2, p3);
      }
      ps += __shfl_xor(ps, 16);
      ps += __shfl_xor(ps, 32);
      l_r[g] += ps;
    }

    // PV: O^T += V^T P^T ; V^T frags shared across both q-groups
#pragma unroll
    for (int c = 0; c < 2; ++c) {
      const int c2 = 2 * c;
      U8 pu[2];
#pragma unroll
      for (int g = 0; g < 2; ++g) {
        u32 a0 = (u32)__shfl((int)pk[g][c2][0], src0);
        u32 b0 = (u32)__shfl((int)pk[g][c2 + 1][0], src0);
        u32 a1 = (u32)__shfl((int)pk[g][c2][1], src0);
        u32 b1 = (u32)__shfl((int)pk[g][c2 + 1][1], src0);
        u32 a2 = (u32)__shfl((int)pk[g][c2][0], src1);
        u32 b2 = (u32)__shfl((int)pk[g][c2 + 1][0], src1);
        u32 a3 = (u32)__shfl((int)pk[g][c2][1], src1);
        u32 b3 = (u32)__shfl((int)pk[g][c2 + 1][1], src1);
        pu[g].u[0] = half ? b0 : a0;
        pu[g].u[1] = half ? b1 : a1;
        pu[g].u[2] = half ? b2 : a2;
        pu[g].u[3] = half ? b3 : a3;
      }
#pragma unroll
      for (int df = 0; df < 8; ++df) {
        bf16x8 vf = *(const bf16x8*)(vt + (df * 16 + l15) * 72 + c * 32 + l4 * 8);
        accO[0][df] = __builtin_amdgcn_mfma_f32_16x16x32_bf16(vf, pu[0].v, accO[0][df], 0, 0, 0);
        accO[1][df] = __builtin_amdgcn_mfma_f32_16x16x32_bf16(vf, pu[1].v, accO[1][df], 0, 0, 0);
      }
    }

    if (pre) writeV(cur ^ 1, vreg);  // T14: write-late after PV
    __syncthreads();
  }

  // epilogue: divide, transpose O^T -> O via per-wave LDS, coalesced store
  float* Obuf = (float*)(smem + w * 8448);  // 16 x 132 f32, wave-private
  const int l31 = lane & 31;
#pragma unroll
  for (int g = 0; g < 2; ++g) {
    float inv = 1.f / l_r[g];
#pragma unroll
    for (int df = 0; df < 8; ++df) {
      f32x4 v = accO[g][df];
#pragma unroll
      for (int j = 0; j < 4; ++j) v[j] *= inv;
      *(f32x4*)&Obuf[l15 * 132 + df * 16 + l4 * 4] = v;
    }
#pragma unroll
    for (int p = 0; p < 8; ++p) {
      int row = p * 2 + (lane >> 5);
      f32x4 v = *(const f32x4*)&Obuf[row * 132 + l31 * 4];
      int qg = q0 + w * 32 + g * 16 + row;
      *(f32x4*)&Out[(size_t)(bb * N_ + qg) * D_ + h * HD + l31 * 4] = v;
    }
  }
}

extern "C" void kernel_launch(void* const* d_in, const int* in_sizes, int n_in,
                              void* d_out, int out_size, void* d_ws, size_t ws_size,
                              hipStream_t stream) {
  const float* x  = (const float*)d_in[0];
  const float* Wq = (const float*)d_in[1];
  const float* bq = (const float*)d_in[2];
  float* out = (float*)d_out;
  char* ws = (char*)d_ws;

  u16* Qb  = (u16*)(ws);
  u16* Kb  = (u16*)(ws + 16777216);
  u16* Vb  = (u16*)(ws + 2 * 16777216);
  u16* Xb  = (u16*)(ws + 3 * 16777216);
  u16* Wb  = (u16*)(ws + 4 * 16777216);
  float* tbl = (float*)(ws + 4 * 16777216 + 25165824);

  cvt_kernel<<<2048, 256, 0, stream>>>(x, Xb, (B_ * N_ * D_) / 4);
  cvt_kernel<<<2048, 256, 0, stream>>>(Wq, Wb, (3 * D_ * D_) / 4);
  rope_tbl_kernel<<<(N_ * 32 + 255) / 256, 256, 0, stream>>>(tbl);
  qkv_gemm_kernel<<<512, 512, 0, stream>>>(Xb, Wb, bq, tbl, Qb, Kb, Vb);
  flash_kernel<<<512, 256, 0, stream>>>(Qb, Kb, Vb, out);
}

// Round 7
// 251.009 us; speedup vs baseline: 1.4911x; 1.0137x over previous
//
#include <hip/hip_runtime.h>
#include <hip/hip_bf16.h>
#include <math.h>

typedef unsigned short u16;
typedef unsigned int u32;
typedef __attribute__((ext_vector_type(8))) short bf16x8;
typedef __attribute__((ext_vector_type(4))) float f32x4;

#define B_ 2
#define N_ 2048
#define D_ 2048
#define H_ 16
#define HD 128
#define GK 2048

__device__ __forceinline__ u16 f2bf(float f) {
  u32 u = __float_as_uint(f);
  u = (u + 0x7fffu + ((u >> 16) & 1u)) >> 16;  // RNE
  return (u16)u;
}

__device__ __forceinline__ u32 cvtpk(float lo, float hi) {
  u32 r;
  asm("v_cvt_pk_bf16_f32 %0, %1, %2" : "=v"(r) : "v"(lo), "v"(hi));
  return r;
}

__device__ __forceinline__ void gload_lds16(const void* g, void* l) {
  __builtin_amdgcn_global_load_lds(
      (const __attribute__((address_space(1))) u32*)g,
      (__attribute__((address_space(3))) u32*)l, 16, 0, 0);
}

// ---------------- fp32 -> bf16 convert ----------------
__global__ __launch_bounds__(256) void cvt_kernel(const float* __restrict__ in,
                                                  u16* __restrict__ out, int n4) {
  int i = blockIdx.x * blockDim.x + threadIdx.x;
  int st = gridDim.x * blockDim.x;
  for (; i < n4; i += st) {
    float4 v = ((const float4*)in)[i];
    ushort4 o;
    o.x = f2bf(v.x); o.y = f2bf(v.y); o.z = f2bf(v.z); o.w = f2bf(v.w);
    ((ushort4*)out)[i] = o;
  }
}

// ---------------- RoPE cos/sin table: [pos][32] pairs ----------------
__global__ __launch_bounds__(256) void rope_tbl_kernel(float* __restrict__ tbl) {
  int i = blockIdx.x * blockDim.x + threadIdx.x;
  if (i >= N_ * 32) return;
  int pos = i >> 5, p = i & 31;
  double inv = pow(10000.0, -(double)p / 32.0);
  double a = (double)pos * inv;
  tbl[2 * i]     = (float)cos(a);
  tbl[2 * i + 1] = (float)sin(a);
}

// ---------------- QKV GEMM: 256x192 tile, BK=64 ----------------
// 8 waves (2M x 4N). LDS 144KB: A tri-buf 3x32KB, B dbuf 2x24KB.
// ONE barrier + ONE counted vmcnt(4) per K-tile; no intra-tile barriers.
// Sync proof: buffer staged in tile T first read in T+1 (B) / T+2 (A);
// re-stage targets finished before previous end-of-tile barrier. At the
// vmcnt point of tile T, outstanding = B(T+1)x3 + A(T+2)x4 -> vmcnt(4)
// guarantees everything tile T+1 reads has landed. Reads & MFMA clusters
// interleave freely inside the tile (compiler lgkmcnt, wave drift).
__global__ __launch_bounds__(512, 2) void qkv_gemm_kernel(
    const u16* __restrict__ X, const u16* __restrict__ W,
    const float* __restrict__ bias, const float* __restrict__ tbl,
    u16* __restrict__ Qo, u16* __restrict__ Ko, u16* __restrict__ Vo) {
  __shared__ char smem[147456];  // A: 3x32KB | B: 2x24KB at +98304
  const int tid = threadIdx.x;
  const int lane = tid & 63;
  const int w = tid >> 6;            // 0..7
  const int wm = w >> 2, wn = w & 3; // 2M x 4N waves
  const int l15 = lane & 15, l4 = lane >> 4;

  // bijective XCD-chunk swizzle: 512 wgs, 8 XCDs, 64 contiguous per XCD
  const int bid = blockIdx.x;
  const int wg = (bid & 7) * 64 + (bid >> 3);
  const int n0 = (wg & 31) * 192;
  const int m0 = (wg >> 5) * 256;

  // read-side swizzled in-row byte offsets (XOR may flip bit6 = k-half bit)
  const int aof0 = (l4 * 16) ^ ((l15 & 7) << 4);
  const int aof1 = (64 + l4 * 16) ^ ((l15 & 7) << 4);

  // stage-side precompute (inverse swizzle of per-thread chunk slot)
  int srowA[2], scolA[2];
#pragma unroll
  for (int p = 0; p < 2; ++p) {
    int o = (w * 2 + p) * 1024 + lane * 16;
    int lo = o ^ (((o >> 7) & 7) << 4);
    srowA[p] = lo >> 7;
    scolA[p] = (lo & 127) >> 1;
  }
  const int oB = w * 1024 + lane * 16;
  const int loB = oB ^ (((oB >> 7) & 7) << 4);
  const int srowB = loB >> 7, scolB = (loB & 127) >> 1;

  f32x4 acc[8][3];
#pragma unroll
  for (int fm = 0; fm < 8; ++fm)
#pragma unroll
    for (int fn = 0; fn < 3; ++fn)
#pragma unroll
      for (int q = 0; q < 4; ++q) acc[fm][fn][q] = 0.f;

  auto stageA = [&](char* Abase, int half, int k0) {
#pragma unroll
    for (int p = 0; p < 2; ++p) {
      gload_lds16(X + (size_t)(m0 + half * 128 + srowA[p]) * GK + k0 + scolA[p],
                  Abase + half * 16384 + (w * 2 + p) * 1024);
    }
  };
  auto stageB = [&](char* Bbase, int chunk, int k0) {
    gload_lds16(W + (size_t)(n0 + chunk * 64 + srowB) * GK + k0 + scolB,
                Bbase + chunk * 8192 + w * 1024);
  };

  const int NK = GK / 64;  // 32

  // prologue: A(0), B(0), A(1); wait first 7 landed, keep A(1)'s 4 in flight
  stageA(smem, 0, 0); stageA(smem, 1, 0);
  stageB(smem + 98304, 0, 0); stageB(smem + 98304, 1, 0); stageB(smem + 98304, 2, 0);
  stageA(smem + 32768, 0, 64); stageA(smem + 32768, 1, 64);
  asm volatile("s_waitcnt vmcnt(4)" ::: "memory");
  __builtin_amdgcn_s_barrier();

  int at = 0;  // A-buf holding tile T
  for (int T = 0; T < NK; ++T) {
    const int bt = T & 1;
    int an2 = at + 2; if (an2 >= 3) an2 -= 3;
    const char* Ab = smem + at * 32768 + wm * 16384;
    const char* Bb = smem + 98304 + bt * 24576;
    char* Bn = smem + 98304 + (bt ^ 1) * 24576;
    char* An = smem + an2 * 32768;
    const int kn1 = (T + 1) * 64, kn2 = (T + 2) * 64;
    const bool hasB = (T + 1 < NK), hasA = (T + 2 < NK);

    bf16x8 bl[3], bh[3], aq[4];

    // ---- k-half 0, m-quad 0; issue next-tile B stages
#pragma unroll
    for (int fn = 0; fn < 3; ++fn)
      bl[fn] = *(const bf16x8*)(Bb + (wn * 48 + fn * 16 + l15) * 128 + aof0);
#pragma unroll
    for (int fm = 0; fm < 4; ++fm)
      aq[fm] = *(const bf16x8*)(Ab + (fm * 16 + l15) * 128 + aof0);
    if (hasB) { stageB(Bn, 0, kn1); stageB(Bn, 1, kn1); stageB(Bn, 2, kn1); }
    __builtin_amdgcn_s_setprio(1);
#pragma unroll
    for (int fm = 0; fm < 4; ++fm)
#pragma unroll
      for (int fn = 0; fn < 3; ++fn)
        acc[fm][fn] = __builtin_amdgcn_mfma_f32_16x16x32_bf16(aq[fm], bl[fn], acc[fm][fn], 0, 0, 0);
    __builtin_amdgcn_s_setprio(0);

    // ---- k-half 0, m-quad 1
#pragma unroll
    for (int fm = 0; fm < 4; ++fm)
      aq[fm] = *(const bf16x8*)(Ab + ((fm + 4) * 16 + l15) * 128 + aof0);
    __builtin_amdgcn_s_setprio(1);
#pragma unroll
    for (int fm = 0; fm < 4; ++fm)
#pragma unroll
      for (int fn = 0; fn < 3; ++fn)
        acc[fm + 4][fn] = __builtin_amdgcn_mfma_f32_16x16x32_bf16(aq[fm], bl[fn], acc[fm + 4][fn], 0, 0, 0);
    __builtin_amdgcn_s_setprio(0);

    // ---- k-half 1, m-quad 0; issue A(T+2) stages into third buffer
#pragma unroll
    for (int fn = 0; fn < 3; ++fn)
      bh[fn] = *(const bf16x8*)(Bb + (wn * 48 + fn * 16 + l15) * 128 + aof1);
#pragma unroll
    for (int fm = 0; fm < 4; ++fm)
      aq[fm] = *(const bf16x8*)(Ab + (fm * 16 + l15) * 128 + aof1);
    if (hasA) { stageA(An, 0, kn2); stageA(An, 1, kn2); }
    __builtin_amdgcn_s_setprio(1);
#pragma unroll
    for (int fm = 0; fm < 4; ++fm)
#pragma unroll
      for (int fn = 0; fn < 3; ++fn)
        acc[fm][fn] = __builtin_amdgcn_mfma_f32_16x16x32_bf16(aq[fm], bh[fn], acc[fm][fn], 0, 0, 0);
    __builtin_amdgcn_s_setprio(0);

    // ---- k-half 1, m-quad 1; counted vmcnt then single end-of-tile barrier
#pragma unroll
    for (int fm = 0; fm < 4; ++fm)
      aq[fm] = *(const bf16x8*)(Ab + ((fm + 4) * 16 + l15) * 128 + aof1);
    if (hasA) {
      asm volatile("s_waitcnt vmcnt(4)" ::: "memory");  // T+1 landed; A(T+2) in flight
    } else {
      asm volatile("s_waitcnt vmcnt(0)" ::: "memory");  // tail drain
    }
    __builtin_amdgcn_s_setprio(1);
#pragma unroll
    for (int fm = 0; fm < 4; ++fm)
#pragma unroll
      for (int fn = 0; fn < 3; ++fn)
        acc[fm + 4][fn] = __builtin_amdgcn_mfma_f32_16x16x32_bf16(aq[fm], bh[fn], acc[fm + 4][fn], 0, 0, 0);
    __builtin_amdgcn_s_setprio(0);
    __builtin_amdgcn_s_barrier();

    at = (at + 1 == 3) ? 0 : at + 1;
  }

  // epilogue: bias + RoPE (q,k sections, d<64) + scatter; Q pre-scaled
  const float QSCALE = 0.08838834764831845f;  // 1/sqrt(128)
#pragma unroll
  for (int fn = 0; fn < 3; ++fn) {
    int gn = n0 + wn * 48 + fn * 16 + l15;
    float bv = bias[gn];
    int sec = gn >> 11;
    int wi = gn & 2047;
    int h = wi >> 7;
    int d = wi & 127;
    u16* dstbase = (sec == 0) ? Qo : (sec == 1) ? Ko : Vo;
    float mulf = (sec == 0) ? QSCALE : 1.f;
    bool doRope = (sec < 2) && (d < 64);
    int pidx = d >> 1;
    bool odd = (d & 1) != 0;
#pragma unroll
    for (int fm = 0; fm < 8; ++fm) {
#pragma unroll
      for (int j = 0; j < 4; ++j) {
        int gm = m0 + wm * 128 + fm * 16 + l4 * 4 + j;
        int bb = gm >> 11;
        int pos = gm & 2047;
        float v = acc[fm][fn][j] + bv;
        float pr = __shfl_xor(v, 1);
        float ov = v;
        if (doRope) {
          float2 cs = ((const float2*)tbl)[pos * 32 + pidx];
          ov = odd ? (v * cs.x + pr * cs.y) : (v * cs.x - pr * cs.y);
        }
        dstbase[(size_t)((bb * H_ + h) * N_ + pos) * HD + d] = f2bf(ov * mulf);
      }
    }
  }
}

// ---------------- causal flash attention ----------------
// 512 blocks (1-D), 4 waves x 32 q-rows = 128 q-rows/block. KVBLK=64,
// double-buffered K/V, one barrier/tile, T14 staged V, defer-max softmax.
// LPT dispatch (longest tiles first) + XCD-chunked bh mapping for L2.
__global__ __launch_bounds__(256, 2) void flash_kernel(
    const u16* __restrict__ Q, const u16* __restrict__ K, const u16* __restrict__ V,
    float* __restrict__ Out) {
  __shared__ char smem[69632];  // K dbuf 2x16KB | V dbuf 2x18KB

  const int tid = threadIdx.x, lane = tid & 63, w = tid >> 6;
  const int l15 = lane & 15, l4 = lane >> 4;

  const int bid = blockIdx.x;
  const int xcd = bid & 7, slot = bid >> 3;
  const int bh = xcd * 4 + (slot >> 4);   // 4 bh per XCD -> K/V fits 4MB L2
  const int x = 15 - (slot & 15);         // LPT: longest q-tiles dispatch first
  const int bb = bh >> 4, h = bh & 15;
  const size_t base = (size_t)bh * (N_ * HD);
  const int q0 = x * 128;
  const int nt = 2 * x + 2;

  // Q B-frags for two 16-row groups (col q = l15, k rows d = kf*32 + l4*8)
  bf16x8 qf[2][4];
#pragma unroll
  for (int g = 0; g < 2; ++g) {
    const u16* qp = Q + base + (size_t)(q0 + w * 32 + g * 16 + l15) * HD + l4 * 8;
#pragma unroll
    for (int kf = 0; kf < 4; ++kf) qf[g][kf] = *(const bf16x8*)(qp + kf * 32);
  }

  float m_r[2] = {-1e30f, -1e30f}, l_r[2] = {0.f, 0.f};
  f32x4 accO[2][8];
#pragma unroll
  for (int g = 0; g < 2; ++g)
#pragma unroll
    for (int df = 0; df < 8; ++df)
#pragma unroll
      for (int q = 0; q < 4; ++q) accO[g][df][q] = 0.f;

  auto stageK = [&](int buf, int t0) {
    const u16* kb = K + base + (size_t)t0 * HD;
    char* kt = smem + buf * 16384;
#pragma unroll
    for (int i = 0; i < 4; ++i) {
      int c = w * 4 + i;
      int o = c * 1024 + lane * 16;
      int lo = o ^ (((o >> 8) & 7) << 4);
      gload_lds16(kb + (lo >> 1), kt + c * 1024);
    }
  };
  auto loadV = [&](int t0, bf16x8* vr) {
    const u16* vp = V + base + (size_t)(t0 + lane) * HD + w * 32;
#pragma unroll
    for (int i = 0; i < 4; ++i) vr[i] = *(const bf16x8*)(vp + i * 8);
  };
  auto writeV = [&](int buf, const bf16x8* vr) {
    u16* vt = (u16*)(smem + 32768 + buf * 18432);
#pragma unroll
    for (int i = 0; i < 4; ++i)
#pragma unroll
      for (int jj = 0; jj < 8; ++jj)
        vt[(w * 32 + i * 8 + jj) * 72 + lane] = (u16)vr[i][jj];
  };

  const int src0 = l15 + 32 * (l4 & 1);
  const int src1 = src0 + 16;
  const int half = l4 >> 1;
  union U8 { u32 u[4]; bf16x8 v; };

  bf16x8 vreg[4];
  stageK(0, 0);
  loadV(0, vreg);
  writeV(0, vreg);
  __syncthreads();

  for (int t = 0; t < nt; ++t) {
    const int cur = t & 1;
    const int t0 = t * 64;
    const bool pre = (t + 1 < nt);
    if (pre) { stageK(cur ^ 1, t0 + 64); loadV(t0 + 64, vreg); }

    const char* kt = smem + cur * 16384;
    const u16* vt = (const u16*)(smem + 32768 + cur * 18432);

    // S^T = K Q^T: lane holds S[kv = cf*16 + l4*4 + j][q = l15] per group
    f32x4 s[2][4];
#pragma unroll
    for (int cf = 0; cf < 4; ++cf) {
#pragma unroll
      for (int q = 0; q < 4; ++q) { s[0][cf][q] = 0.f; s[1][cf][q] = 0.f; }
      int row = cf * 16 + l15;
      int sw = (row & 7) << 4;
#pragma unroll
      for (int kf = 0; kf < 4; ++kf) {
        int off = (row * 256 + kf * 64 + l4 * 16) ^ sw;
        bf16x8 kfrag = *(const bf16x8*)(kt + off);
        s[0][cf] = __builtin_amdgcn_mfma_f32_16x16x32_bf16(kfrag, qf[0][kf], s[0][cf], 0, 0, 0);
        s[1][cf] = __builtin_amdgcn_mfma_f32_16x16x32_bf16(kfrag, qf[1][kf], s[1][cf], 0, 0, 0);
      }
    }

    u32 pk[2][4][2];
#pragma unroll
    for (int g = 0; g < 2; ++g) {
      const int qbase = q0 + w * 32 + g * 16;
      if (t0 + 63 > qbase) {  // diagonal: causal mask
        const int qg = qbase + l15;
#pragma unroll
        for (int cf = 0; cf < 4; ++cf)
#pragma unroll
          for (int j = 0; j < 4; ++j) {
            int kvg = t0 + cf * 16 + l4 * 4 + j;
            if (kvg > qg) s[g][cf][j] = -1e30f;
          }
      }
      // per-q max: in-lane 16 + cross-group reduce
      float pmax = s[g][0][0];
#pragma unroll
      for (int cf = 0; cf < 4; ++cf)
#pragma unroll
        for (int j = 0; j < 4; ++j) pmax = fmaxf(pmax, s[g][cf][j]);
      pmax = fmaxf(pmax, __shfl_xor(pmax, 16));
      pmax = fmaxf(pmax, __shfl_xor(pmax, 32));

      if (!__all(pmax <= m_r[g] + 8.f)) {  // T13 defer-max
        float mn = fmaxf(m_r[g], pmax);
        float rs = __expf(m_r[g] - mn);
        m_r[g] = mn;
        l_r[g] *= rs;
#pragma unroll
        for (int df = 0; df < 8; ++df)
#pragma unroll
          for (int j = 0; j < 4; ++j) accO[g][df][j] *= rs;
      }

      float ps = 0.f;
#pragma unroll
      for (int cf = 0; cf < 4; ++cf) {
        float p0 = __expf(s[g][cf][0] - m_r[g]);
        float p1 = __expf(s[g][cf][1] - m_r[g]);
        float p2 = __expf(s[g][cf][2] - m_r[g]);
        float p3 = __expf(s[g][cf][3] - m_r[g]);
        ps += (p0 + p1) + (p2 + p3);
        pk[g][cf][0] = cvtpk(p0, p1);
        pk[g][cf][1] = cvtpk(p2, p3);
      }
      ps += __shfl_xor(ps, 16);
      ps += __shfl_xor(ps, 32);
      l_r[g] += ps;
    }

    // PV: O^T += V^T P^T ; V^T frags shared across both q-groups
#pragma unroll
    for (int c = 0; c < 2; ++c) {
      const int c2 = 2 * c;
      U8 pu[2];
#pragma unroll
      for (int g = 0; g < 2; ++g) {
        u32 a0 = (u32)__shfl((int)pk[g][c2][0], src0);
        u32 b0 = (u32)__shfl((int)pk[g][c2 + 1][0], src0);
        u32 a1 = (u32)__shfl((int)pk[g][c2][1], src0);
        u32 b1 = (u32)__shfl((int)pk[g][c2 + 1][1], src0);
        u32 a2 = (u32)__shfl((int)pk[g][c2][0], src1);
        u32 b2 = (u32)__shfl((int)pk[g][c2 + 1][0], src1);
        u32 a3 = (u32)__shfl((int)pk[g][c2][1], src1);
        u32 b3 = (u32)__shfl((int)pk[g][c2 + 1][1], src1);
        pu[g].u[0] = half ? b0 : a0;
        pu[g].u[1] = half ? b1 : a1;
        pu[g].u[2] = half ? b2 : a2;
        pu[g].u[3] = half ? b3 : a3;
      }
#pragma unroll
      for (int df = 0; df < 8; ++df) {
        bf16x8 vf = *(const bf16x8*)(vt + (df * 16 + l15) * 72 + c * 32 + l4 * 8);
        accO[0][df] = __builtin_amdgcn_mfma_f32_16x16x32_bf16(vf, pu[0].v, accO[0][df], 0, 0, 0);
        accO[1][df] = __builtin_amdgcn_mfma_f32_16x16x32_bf16(vf, pu[1].v, accO[1][df], 0, 0, 0);
      }
    }

    if (pre) writeV(cur ^ 1, vreg);  // T14: write-late after PV
    __syncthreads();
  }

  // epilogue: divide, transpose O^T -> O via per-wave LDS, coalesced store
  float* Obuf = (float*)(smem + w * 8448);  // 16 x 132 f32, wave-private
  const int l31 = lane & 31;
#pragma unroll
  for (int g = 0; g < 2; ++g) {
    float inv = 1.f / l_r[g];
#pragma unroll
    for (int df = 0; df < 8; ++df) {
      f32x4 v = accO[g][df];
#pragma unroll
      for (int j = 0; j < 4; ++j) v[j] *= inv;
      *(f32x4*)&Obuf[l15 * 132 + df * 16 + l4 * 4] = v;
    }
#pragma unroll
    for (int p = 0; p < 8; ++p) {
      int row = p * 2 + (lane >> 5);
      f32x4 v = *(const f32x4*)&Obuf[row * 132 + l31 * 4];
      int qg = q0 + w * 32 + g * 16 + row;
      *(f32x4*)&Out[(size_t)(bb * N_ + qg) * D_ + h * HD + l31 * 4] = v;
    }
  }
}

extern "C" void kernel_launch(void* const* d_in, const int* in_sizes, int n_in,
                              void* d_out, int out_size, void* d_ws, size_t ws_size,
                              hipStream_t stream) {
  const float* x  = (const float*)d_in[0];
  const float* Wq = (const float*)d_in[1];
  const float* bq = (const float*)d_in[2];
  float* out = (float*)d_out;
  char* ws = (char*)d_ws;

  u16* Qb  = (u16*)(ws);
  u16* Kb  = (u16*)(ws + 16777216);
  u16* Vb  = (u16*)(ws + 2 * 16777216);
  u16* Xb  = (u16*)(ws + 3 * 16777216);
  u16* Wb  = (u16*)(ws + 4 * 16777216);
  float* tbl = (float*)(ws + 4 * 16777216 + 25165824);

  cvt_kernel<<<2048, 256, 0, stream>>>(x, Xb, (B_ * N_ * D_) / 4);
  cvt_kernel<<<2048, 256, 0, stream>>>(Wq, Wb, (3 * D_ * D_) / 4);
  rope_tbl_kernel<<<(N_ * 32 + 255) / 256, 256, 0, stream>>>(tbl);
  qkv_gemm_kernel<<<512, 512, 0, stream>>>(Xb, Wb, bq, tbl, Qb, Kb, Vb);
  flash_kernel<<<512, 256, 0, stream>>>(Qb, Kb, Vb, out);
}